// Round 4
// baseline (1278.677 us; speedup 1.0000x reference)
//
#include <hip/hip_runtime.h>
#include <hip/hip_bf16.h>
#include <math.h>

#define L2E 1.4426950408889634f
#define T_STEPS 8192
#define KTOT 5104   // 8 channels * 638 spatial (22*29)
#define EPS_LTC 1e-8f

// scan chunking: 256 chunks x 32 steps, 16-step burn-in (contraction <=0.9/unfold
// => init error decays by >=0.9^96 ~ 4e-5; typical far smaller)
#define CHUNKS 256
#define S_PER  32
#define WARM   16

__device__ __forceinline__ float softplus_f(float x) {
    return log1pf(expf(-fabsf(x))) + fmaxf(x, 0.f);
}

// ---------------------------------------------------------------------------
// K0: parameter precompute (tiny).
// ---------------------------------------------------------------------------
__global__ void k0_precompute(
    const float* __restrict__ sw, const float* __restrict__ smu,
    const float* __restrict__ ssig, const float* __restrict__ serev,
    const float* __restrict__ smask,
    const float* __restrict__ w, const float* __restrict__ mu,
    const float* __restrict__ sigma, const float* __restrict__ erev,
    const float* __restrict__ mask,
    const float* __restrict__ gleak, const float* __restrict__ vleak,
    const float* __restrict__ cm,
    float* __restrict__ sc1, float* __restrict__ sc0,
    float* __restrict__ swe, float* __restrict__ swp,
    float* __restrict__ rc1, float* __restrict__ rc0,
    float* __restrict__ rwe, float* __restrict__ rwp,
    float* __restrict__ neu)
{
    int t = threadIdx.x;
    if (t < 608) {   // sensory (32 x 19)
        float sp = softplus_f(sw[t]);
        float c1 = ssig[t] * L2E;
        sc1[t] = c1;
        sc0[t] = c1 * smu[t];
        swe[t] = sp * serev[t];   // serev already carries mask
        swp[t] = sp * smask[t];
    }
    if (t < 361) {   // recurrent (19 x 19), layout [src*19 + tgt]
        float wp = softplus_f(w[t]) * mask[t];
        float c1 = sigma[t] * L2E;
        rc1[t] = c1;
        rc0[t] = c1 * mu[t];
        rwe[t] = wp * erev[t];
        rwp[t] = wp;
    }
    if (t < 64) {
        if (t < 19) {
            float g   = softplus_f(gleak[t]);
            float cmt = softplus_f(cm[t]) * 6.f;   // ODE_UNFOLDS
            neu[t]       = cmt;
            neu[64 + t]  = g * vleak[t];
            neu[128 + t] = cmt + g + EPS_LTC;
        } else {
            neu[t] = 0.f; neu[64 + t] = 0.f; neu[128 + t] = 1.f;  // benign pad
        }
    }
}

// ---------------------------------------------------------------------------
// K12 v3: fused conv+fc1+fc2+sensory front-end.
//  - 256 blocks x 128 threads (2 waves), 32-sample x 64-out tile
//  - 4x4 micro-tile: 2x ds_read_b128 per 16 FMA (was b32+b128 per 4 FMA)
//  - K iterated channel-INNER (chunk = 8 spatial positions x 8 channels):
//    the 8 lanes sharing a spatial position read identical x addresses ->
//    in-wave dedup, x fetched ~once from HBM (was 8x -> 252 MB FETCH)
// ---------------------------------------------------------------------------
__global__ __launch_bounds__(128) void k12_frontend(
    const float* __restrict__ x, const float* __restrict__ conv_w,
    const float* __restrict__ conv_b,
    const float* __restrict__ fc1_w, const float* __restrict__ fc1_b,
    const float* __restrict__ fc2_w, const float* __restrict__ fc2_b,
    const float* __restrict__ iw, const float* __restrict__ ib,
    const float* __restrict__ sc1, const float* __restrict__ sc0,
    const float* __restrict__ swe, const float* __restrict__ swp,
    float* __restrict__ wn_s, float* __restrict__ wd_s)
{
    __shared__ __align__(16) float smem[6760];
    float* yS  = smem;          // [qq][sample] stride 36 (2304f); later hS [sample][out] stride 68 (2176f)
    float* wS  = smem + 2304;   // [qq][out] stride 68 (4352f); later w2S(2080)+seqS(1056)
    float* cwS = smem + 6656;   // 96
    float* cbS = smem + 6752;   // 8

    const int t  = threadIdx.x;     // 0..127
    const int b0 = blockIdx.x * 32;
    if (t < 96) cwS[t] = conv_w[t];
    if (t < 8)  cbS[t] = conv_b[t];

    const int wv = t >> 6;          // wave 0/1
    const int qq = t & 63;          // position within K-chunk
    const int o  = qq >> 3;         // conv output channel 0..7
    const int rr = qq & 7;          // spatial offset within chunk
    const int sg = t >> 4;          // sample group 0..7  (owns samples 4sg..4sg+3)
    const int og = t & 15;          // out group 0..15    (owns outs 4og..4og+3)

    float acc[4][4] = {};
    __syncthreads();

    for (int k0c = 0; k0c < 80; k0c++) {
        const int r  = k0c * 8 + rr;        // spatial index 0..639
        const bool qv = (r < 638);
        const int k  = o * 638 + r;         // fc1 K index (k = o*638 + r)

        // ---- weight tile 64q x 64n ----
        const float* fw = fc1_w + k;
        #pragma unroll
        for (int e = 0; e < 32; e++) {
            int nl = e * 2 + wv;
            wS[qq * 68 + nl] = qv ? fw[nl * KTOT] : 0.f;
        }

        // ---- A tile 64q x 32 samples: conv + ELU on the fly ----
        int oh = r / 29;
        int ow = r - oh * 29;
        const float* xb = x + (size_t)b0 * 2070 + oh * 30 + ow;
        #pragma unroll
        for (int e = 0; e < 16; e++) {
            int bl = e * 2 + wv;
            float v = 0.f;
            if (qv) {
                const float* xp = xb + bl * 2070;
                v = cbS[o];
                #pragma unroll
                for (int cc = 0; cc < 3; cc++) {
                    const float* xq = xp + cc * 690;
                    const float* wq = cwS + (o * 3 + cc) * 4;
                    v = fmaf(xq[0],  wq[0], v);
                    v = fmaf(xq[1],  wq[1], v);
                    v = fmaf(xq[30], wq[2], v);
                    v = fmaf(xq[31], wq[3], v);
                }
                v = (v > 0.f) ? v : expm1f(v);   // ELU
            }
            yS[qq * 36 + bl] = v;
        }
        __syncthreads();

        // ---- 32x64x64 outer product, 4x4 micro-tile ----
        #pragma unroll 8
        for (int kk = 0; kk < 64; kk++) {
            const float4 ya = *(const float4*)&yS[kk * 36 + 4 * sg];
            const float4 wa = *(const float4*)&wS[kk * 68 + 4 * og];
            const float yv[4] = {ya.x, ya.y, ya.z, ya.w};
            const float wv4[4] = {wa.x, wa.y, wa.z, wa.w};
            #pragma unroll
            for (int i = 0; i < 4; i++)
                #pragma unroll
                for (int j = 0; j < 4; j++)
                    acc[i][j] = fmaf(yv[i], wv4[j], acc[i][j]);
        }
        __syncthreads();
    }

    // ---- h tile (ReLU(acc+b)) -> LDS (reuse yS region, stride 68) ----
    float* hS = yS;
    {
        const float4 bb = *(const float4*)&fc1_b[4 * og];
        #pragma unroll
        for (int i = 0; i < 4; i++) {
            float4 hv;
            hv.x = fmaxf(acc[i][0] + bb.x, 0.f);
            hv.y = fmaxf(acc[i][1] + bb.y, 0.f);
            hv.z = fmaxf(acc[i][2] + bb.z, 0.f);
            hv.w = fmaxf(acc[i][3] + bb.w, 0.f);
            *(float4*)&hS[(4 * sg + i) * 68 + 4 * og] = hv;
        }
    }
    // ---- stage fc2 weights (reuse wS region) ----
    float* w2S  = wS;          // [s][n] stride 65 (2080 f)
    float* seqS = wS + 2080;   // [sample][s] stride 33 (1056 f)
    #pragma unroll
    for (int e = 0; e < 16; e++) {
        int flat = e * 128 + t;           // 2048 = 32*64
        int s = flat >> 6, n = flat & 63;
        w2S[s * 65 + n] = fc2_w[flat];
    }
    __syncthreads();

    // ---- fc2 + input affine -> seq (32 samples x 32 sensory) ----
    #pragma unroll
    for (int e = 0; e < 8; e++) {
        int flat = e * 128 + t;           // 1024 = 32*32
        int s = flat & 31, bl = flat >> 5;
        float a2 = fc2_b[s];
        #pragma unroll 8
        for (int n = 0; n < 64; n++)
            a2 = fmaf(hS[bl * 68 + n], w2S[s * 65 + n], a2);
        seqS[bl * 33 + s] = a2 * iw[s] + ib[s];
    }
    __syncthreads();

    // ---- sensory synapse sums (32 samples x 19 neurons = 608 items) ----
    #pragma unroll
    for (int e = 0; e < 5; e++) {
        int flat = e * 128 + t;
        if (flat < 608) {
            int n = flat % 19, bl = flat / 19;
            float wn = 0.f, wd = 0.f;
            #pragma unroll
            for (int s = 0; s < 32; s++) {
                float xx = sc0[s * 19 + n] - sc1[s * 19 + n] * seqS[bl * 33 + s];
                float ee = __builtin_amdgcn_exp2f(xx);
                float uu = __builtin_amdgcn_rcpf(1.f + ee);
                wn = fmaf(swe[s * 19 + n], uu, wn);
                wd = fmaf(swp[s * 19 + n], uu, wd);
            }
            wn_s[(b0 + bl) * 19 + n] = wn;
            wd_s[(b0 + bl) * 19 + n] = wd;
        }
    }
}

// ---------------------------------------------------------------------------
// K3P v2: chunk-parallel LTC scan, ONE WAVE per chunk — no barriers, no LDS.
// 64 lanes = 19 cols x 2 halves (p): half p handles srcs p*10..p*10+9.
// v broadcast via ds_bpermute (pull from owner lane = col, p=0 copy);
// cross-half reduce via bpermute(l^32) butterfly (both halves keep full sum,
// so both compute identical v updates).
// ---------------------------------------------------------------------------
__global__ __launch_bounds__(64, 1) void k3p2_scan(
    const float* __restrict__ wn_s, const float* __restrict__ wd_s,
    const float* __restrict__ rc1, const float* __restrict__ rc0,
    const float* __restrict__ rwe, const float* __restrict__ rwp,
    const float* __restrict__ neu,
    const float* __restrict__ out_w, const float* __restrict__ out_b,
    float* __restrict__ out)
{
    const int l    = threadIdx.x;       // 0..63
    const int col  = l & 31;            // target neuron (19 real + 13 pad)
    const int p    = l >> 5;            // source half
    const int cidx = (col < 19) ? col : 0;

    float ca[10], cb[10], cwe[10], cwp[10];
    int gidx[10];                       // bpermute byte index for each src's v
    #pragma unroll
    for (int j = 0; j < 10; j++) {
        int s = p * 10 + j;
        bool e = (col < 19) && (s < 19);
        int idx = e ? (s * 19 + col) : 0;
        ca[j]  = e ? rc1[idx] : 0.f;
        cb[j]  = e ? rc0[idx] : 0.f;
        cwe[j] = e ? rwe[idx] : 0.f;
        cwp[j] = e ? rwp[idx] : 0.f;
        gidx[j] = ((s < 19) ? s : 0) * 4;
    }

    const float cmt  = neu[cidx];
    const float gvl  = neu[64 + cidx];
    const float den0 = neu[128 + cidx];
    const float owv  = out_w[0];
    const float obv  = out_b[0];

    const int c       = blockIdx.x;
    const int s_out   = c * S_PER;
    const int s_begin = (c == 0) ? 0 : (s_out - WARM);
    const int s_end   = s_out + S_PER;
    const int pidx    = (l ^ 32) * 4;   // butterfly partner

    float v = 0.f;
    float wnc = wn_s[s_begin * 19 + cidx];
    float wdc = wd_s[s_begin * 19 + cidx];

    for (int tt = s_begin; tt < s_end; tt++) {
        int nt = (tt + 1 < T_STEPS) ? (tt + 1) : (T_STEPS - 1);
        float wnn = wn_s[nt * 19 + cidx];    // prefetch next step
        float wdn = wd_s[nt * 19 + cidx];

        #pragma unroll
        for (int u = 0; u < 6; u++) {
            float pn = 0.f, pd = 0.f;
            #pragma unroll
            for (int j = 0; j < 10; j++) {
                float vs = __int_as_float(
                    __builtin_amdgcn_ds_bpermute(gidx[j], __float_as_int(v)));
                float xx = cb[j] - ca[j] * vs;
                float ee = __builtin_amdgcn_exp2f(xx);
                float uu = __builtin_amdgcn_rcpf(1.f + ee);
                pn = fmaf(cwe[j], uu, pn);
                pd = fmaf(cwp[j], uu, pd);
            }
            pn += __int_as_float(__builtin_amdgcn_ds_bpermute(pidx, __float_as_int(pn)));
            pd += __int_as_float(__builtin_amdgcn_ds_bpermute(pidx, __float_as_int(pd)));
            float num = fmaf(cmt, v, gvl) + (pn + wnc);
            float den = den0 + pd + wdc;
            v = num * __builtin_amdgcn_rcpf(den);
        }
        if (l == 0 && tt >= s_out) out[tt] = fmaf(v, owv, obv);
        wnc = wnn; wdc = wdn;
    }
}

// ---------------------------------------------------------------------------
extern "C" void kernel_launch(void* const* d_in, const int* in_sizes, int n_in,
                              void* d_out, int out_size, void* d_ws, size_t ws_size,
                              hipStream_t stream) {
    const float* x      = (const float*)d_in[0];
    const float* conv_w = (const float*)d_in[1];
    const float* conv_b = (const float*)d_in[2];
    const float* fc1_w  = (const float*)d_in[3];
    const float* fc1_b  = (const float*)d_in[4];
    const float* fc2_w  = (const float*)d_in[5];
    const float* fc2_b  = (const float*)d_in[6];
    const float* iw     = (const float*)d_in[7];
    const float* ib     = (const float*)d_in[8];
    const float* sw     = (const float*)d_in[9];
    const float* smu    = (const float*)d_in[10];
    const float* ssig   = (const float*)d_in[11];
    const float* serev  = (const float*)d_in[12];
    const float* smask  = (const float*)d_in[13];
    const float* w      = (const float*)d_in[14];
    const float* mu     = (const float*)d_in[15];
    const float* sigma  = (const float*)d_in[16];
    const float* erev   = (const float*)d_in[17];
    const float* mask   = (const float*)d_in[18];
    const float* gleak  = (const float*)d_in[19];
    const float* vleak  = (const float*)d_in[20];
    const float* cm     = (const float*)d_in[21];
    const float* ow     = (const float*)d_in[22];
    const float* ob     = (const float*)d_in[23];

    // ws layout — total 315,584 floats = 1,262,336 bytes. Never grow past
    // ws_size: a 3.36 MB layout corrupted neighboring allocations in R0.
    float* ws   = (float*)d_ws;
    float* wn_s = ws;                    // 8192*19 = 155648
    float* wd_s = wn_s + 155648;         // 155648
    float* sc1  = wd_s + 155648;         // 640 each
    float* sc0  = sc1 + 640;
    float* swe  = sc0 + 640;
    float* swp  = swe + 640;
    float* rc1  = swp + 640;             // 384 each
    float* rc0  = rc1 + 384;
    float* rwe  = rc0 + 384;
    float* rwp  = rwe + 384;
    float* neu  = rwp + 384;             // 192
    (void)ws_size; (void)in_sizes; (void)n_in; (void)out_size;

    hipLaunchKernelGGL(k0_precompute, dim3(1), dim3(640), 0, stream,
        sw, smu, ssig, serev, smask, w, mu, sigma, erev, mask,
        gleak, vleak, cm, sc1, sc0, swe, swp, rc1, rc0, rwe, rwp, neu);

    hipLaunchKernelGGL(k12_frontend, dim3(256), dim3(128), 0, stream,
        x, conv_w, conv_b, fc1_w, fc1_b, fc2_w, fc2_b, iw, ib,
        sc1, sc0, swe, swp, wn_s, wd_s);

    hipLaunchKernelGGL(k3p2_scan, dim3(CHUNKS), dim3(64), 0, stream,
        wn_s, wd_s, rc1, rc0, rwe, rwp, neu, ow, ob, (float*)d_out);
}

// Round 5
// 625.515 us; speedup vs baseline: 2.0442x; 2.0442x over previous
//
#include <hip/hip_runtime.h>
#include <hip/hip_bf16.h>
#include <math.h>

#define L2E 1.4426950408889634f
#define T_STEPS 8192
#define KTOT 5104   // 8 channels * 638 spatial (22*29)
#define EPS_LTC 1e-8f

// scan chunking: 1024 chunks x 8 steps, 16-step burn-in (chunks 0,1 exact).
// Contraction <=0.9/unfold => init error decays >=0.9^96 ~ 4e-5 over warm.
#define SCAN_CHUNKS 1024
#define S_PER  8
#define WARM   16

__device__ __forceinline__ float softplus_f(float x) {
    return log1pf(expf(-fabsf(x))) + fmaxf(x, 0.f);
}

// ---------------------------------------------------------------------------
// K0: parameter precompute (tiny).
// ---------------------------------------------------------------------------
__global__ void k0_precompute(
    const float* __restrict__ sw, const float* __restrict__ smu,
    const float* __restrict__ ssig, const float* __restrict__ serev,
    const float* __restrict__ smask,
    const float* __restrict__ w, const float* __restrict__ mu,
    const float* __restrict__ sigma, const float* __restrict__ erev,
    const float* __restrict__ mask,
    const float* __restrict__ gleak, const float* __restrict__ vleak,
    const float* __restrict__ cm,
    float* __restrict__ sc1, float* __restrict__ sc0,
    float* __restrict__ swe, float* __restrict__ swp,
    float* __restrict__ rc1, float* __restrict__ rc0,
    float* __restrict__ rwe, float* __restrict__ rwp,
    float* __restrict__ neu)
{
    int t = threadIdx.x;
    if (t < 608) {   // sensory (32 x 19)
        float sp = softplus_f(sw[t]);
        float c1 = ssig[t] * L2E;
        sc1[t] = c1;
        sc0[t] = c1 * smu[t];
        swe[t] = sp * serev[t];   // serev already carries mask
        swp[t] = sp * smask[t];
    }
    if (t < 361) {   // recurrent (19 x 19), layout [src*19 + tgt]
        float wp = softplus_f(w[t]) * mask[t];
        float c1 = sigma[t] * L2E;
        rc1[t] = c1;
        rc0[t] = c1 * mu[t];
        rwe[t] = wp * erev[t];
        rwp[t] = wp;
    }
    if (t < 64) {
        if (t < 19) {
            float g   = softplus_f(gleak[t]);
            float cmt = softplus_f(cm[t]) * 6.f;   // ODE_UNFOLDS
            neu[t]       = cmt;
            neu[64 + t]  = g * vleak[t];
            neu[128 + t] = cmt + g + EPS_LTC;
        } else {
            neu[t] = 0.f; neu[64 + t] = 0.f; neu[128 + t] = 1.f;  // benign pad
        }
    }
}

// ---------------------------------------------------------------------------
// K12 v5: fused conv+fc1+fc2+sensory front-end.
//  - 256 blocks x 512 threads (8 waves/CU — R2's proven-occupancy shape)
//  - channel-INNER K order (R3's proven FETCH win: x deduped in-wave)
//  - 2x2 micro-tile: 2x ds_read_b64 per 4 FMA (LDS ~64 clk/CU/kk model)
// ---------------------------------------------------------------------------
__global__ __launch_bounds__(512) void k12_frontend(
    const float* __restrict__ x, const float* __restrict__ conv_w,
    const float* __restrict__ conv_b,
    const float* __restrict__ fc1_w, const float* __restrict__ fc1_b,
    const float* __restrict__ fc2_w, const float* __restrict__ fc2_b,
    const float* __restrict__ iw, const float* __restrict__ ib,
    const float* __restrict__ sc1, const float* __restrict__ sc0,
    const float* __restrict__ swe, const float* __restrict__ swp,
    float* __restrict__ wn_s, float* __restrict__ wd_s)
{
    __shared__ __align__(16) float smem[6760];
    float* yS  = smem;          // [qq][sample] stride 36 (2304f); later hS [sample][out] stride 68 (2176f)
    float* wS  = smem + 2304;   // [qq][out] stride 68 (4352f); later w2S(2080)+seqS(1056)
    float* cwS = smem + 6656;   // 96
    float* cbS = smem + 6752;   // 8

    const int t  = threadIdx.x;     // 0..511
    const int b0 = blockIdx.x * 32;
    if (t < 96) cwS[t] = conv_w[t];
    if (t < 8)  cbS[t] = conv_b[t];

    const int wv = t >> 6;          // wave 0..7
    const int qq = t & 63;          // position within K-chunk
    const int o  = qq >> 3;         // conv output channel 0..7
    const int rr = qq & 7;          // spatial offset within chunk
    const int sg = t >> 5;          // sample group 0..15 (owns samples 2sg..2sg+1)
    const int og = t & 31;          // out group 0..31    (owns outs 2og..2og+1)

    float acc[2][2] = {};
    __syncthreads();

    for (int k0c = 0; k0c < 80; k0c++) {
        const int r  = k0c * 8 + rr;        // spatial index 0..639
        const bool qv = (r < 638);
        const int k  = o * 638 + r;         // fc1 K index

        // ---- weight tile 64q x 64n (8 rows per thread) ----
        const float* fw = fc1_w + k;
        #pragma unroll
        for (int e = 0; e < 8; e++) {
            int nl = e * 8 + wv;
            wS[qq * 68 + nl] = qv ? fw[nl * KTOT] : 0.f;
        }

        // ---- A tile 64q x 32 samples: conv + ELU on the fly (4/thread) ----
        int oh = r / 29;
        int ow = r - oh * 29;
        const float* xb = x + (size_t)b0 * 2070 + oh * 30 + ow;
        #pragma unroll
        for (int e = 0; e < 4; e++) {
            int bl = e * 8 + wv;
            float v = 0.f;
            if (qv) {
                const float* xp = xb + bl * 2070;
                v = cbS[o];
                #pragma unroll
                for (int cc = 0; cc < 3; cc++) {
                    const float* xq = xp + cc * 690;
                    const float* wq = cwS + (o * 3 + cc) * 4;
                    v = fmaf(xq[0],  wq[0], v);
                    v = fmaf(xq[1],  wq[1], v);
                    v = fmaf(xq[30], wq[2], v);
                    v = fmaf(xq[31], wq[3], v);
                }
                v = (v > 0.f) ? v : expm1f(v);   // ELU
            }
            yS[qq * 36 + bl] = v;
        }
        __syncthreads();

        // ---- 32x64x64 outer product, 2x2 micro-tile ----
        #pragma unroll 8
        for (int kk = 0; kk < 64; kk++) {
            const float2 ya = *(const float2*)&yS[kk * 36 + 2 * sg];
            const float2 wa = *(const float2*)&wS[kk * 68 + 2 * og];
            acc[0][0] = fmaf(ya.x, wa.x, acc[0][0]);
            acc[0][1] = fmaf(ya.x, wa.y, acc[0][1]);
            acc[1][0] = fmaf(ya.y, wa.x, acc[1][0]);
            acc[1][1] = fmaf(ya.y, wa.y, acc[1][1]);
        }
        __syncthreads();
    }

    // ---- h tile (ReLU(acc+b)) -> LDS (reuse yS region, stride 68) ----
    float* hS = yS;
    {
        const float2 bb = *(const float2*)&fc1_b[2 * og];
        #pragma unroll
        for (int i = 0; i < 2; i++) {
            float2 hv;
            hv.x = fmaxf(acc[i][0] + bb.x, 0.f);
            hv.y = fmaxf(acc[i][1] + bb.y, 0.f);
            *(float2*)&hS[(2 * sg + i) * 68 + 2 * og] = hv;
        }
    }
    // ---- stage fc2 weights (reuse wS region) ----
    float* w2S  = wS;          // [s][n] stride 65 (2080 f)
    float* seqS = wS + 2080;   // [sample][s] stride 33 (1056 f)
    #pragma unroll
    for (int e = 0; e < 4; e++) {
        int flat = e * 512 + t;           // 2048 = 32*64
        int s = flat >> 6, n = flat & 63;
        w2S[s * 65 + n] = fc2_w[flat];
    }
    __syncthreads();

    // ---- fc2 + input affine -> seq (32 samples x 32 sensory) ----
    #pragma unroll
    for (int e = 0; e < 2; e++) {
        int flat = e * 512 + t;           // 1024 = 32*32
        int s = flat & 31, bl = flat >> 5;
        float a2 = fc2_b[s];
        #pragma unroll 8
        for (int n = 0; n < 64; n++)
            a2 = fmaf(hS[bl * 68 + n], w2S[s * 65 + n], a2);
        seqS[bl * 33 + s] = a2 * iw[s] + ib[s];
    }
    __syncthreads();

    // ---- sensory synapse sums (32 samples x 19 neurons = 608 items) ----
    #pragma unroll
    for (int e = 0; e < 2; e++) {
        int flat = e * 512 + t;
        if (flat < 608) {
            int n = flat % 19, bl = flat / 19;
            float wn = 0.f, wd = 0.f;
            #pragma unroll
            for (int s = 0; s < 32; s++) {
                float xx = sc0[s * 19 + n] - sc1[s * 19 + n] * seqS[bl * 33 + s];
                float ee = __builtin_amdgcn_exp2f(xx);
                float uu = __builtin_amdgcn_rcpf(1.f + ee);
                wn = fmaf(swe[s * 19 + n], uu, wn);
                wd = fmaf(swp[s * 19 + n], uu, wd);
            }
            wn_s[(b0 + bl) * 19 + n] = wn;
            wd_s[(b0 + bl) * 19 + n] = wd;
        }
    }
}

// ---------------------------------------------------------------------------
// K3P v3: chunk-parallel LTC scan, one wave per chunk — no barriers, no LDS.
// Per-unfold cost is quarter-rate transcendental issue (~21 x 16 cyc);
// mitigation = short chunks (24 steps incl warm) x 1024 concurrent blocks
// (4 blocks/CU on distinct SIMDs — no transcendental-pipe contention).
// ---------------------------------------------------------------------------
__global__ __launch_bounds__(64, 1) void k3p2_scan(
    const float* __restrict__ wn_s, const float* __restrict__ wd_s,
    const float* __restrict__ rc1, const float* __restrict__ rc0,
    const float* __restrict__ rwe, const float* __restrict__ rwp,
    const float* __restrict__ neu,
    const float* __restrict__ out_w, const float* __restrict__ out_b,
    float* __restrict__ out)
{
    const int l    = threadIdx.x;       // 0..63
    const int col  = l & 31;            // target neuron (19 real + 13 pad)
    const int p    = l >> 5;            // source half
    const int cidx = (col < 19) ? col : 0;

    float ca[10], cb[10], cwe[10], cwp[10];
    int gidx[10];                       // bpermute byte index for each src's v
    #pragma unroll
    for (int j = 0; j < 10; j++) {
        int s = p * 10 + j;
        bool e = (col < 19) && (s < 19);
        int idx = e ? (s * 19 + col) : 0;
        ca[j]  = e ? rc1[idx] : 0.f;
        cb[j]  = e ? rc0[idx] : 0.f;
        cwe[j] = e ? rwe[idx] : 0.f;
        cwp[j] = e ? rwp[idx] : 0.f;
        gidx[j] = ((s < 19) ? s : 0) * 4;
    }

    const float cmt  = neu[cidx];
    const float gvl  = neu[64 + cidx];
    const float den0 = neu[128 + cidx];
    const float owv  = out_w[0];
    const float obv  = out_b[0];

    const int c       = blockIdx.x;
    const int s_out   = c * S_PER;
    const int s_begin = (s_out > WARM) ? (s_out - WARM) : 0;  // <=WARM -> exact prefix
    const int s_end   = s_out + S_PER;
    const int pidx    = (l ^ 32) * 4;   // butterfly partner

    float v = 0.f;
    float wnc = wn_s[s_begin * 19 + cidx];
    float wdc = wd_s[s_begin * 19 + cidx];

    for (int tt = s_begin; tt < s_end; tt++) {
        int nt = (tt + 1 < T_STEPS) ? (tt + 1) : (T_STEPS - 1);
        float wnn = wn_s[nt * 19 + cidx];    // prefetch next step
        float wdn = wd_s[nt * 19 + cidx];

        #pragma unroll
        for (int u = 0; u < 6; u++) {
            float pn = 0.f, pd = 0.f;
            #pragma unroll
            for (int j = 0; j < 10; j++) {
                float vs = __int_as_float(
                    __builtin_amdgcn_ds_bpermute(gidx[j], __float_as_int(v)));
                float xx = cb[j] - ca[j] * vs;
                float ee = __builtin_amdgcn_exp2f(xx);
                float uu = __builtin_amdgcn_rcpf(1.f + ee);
                pn = fmaf(cwe[j], uu, pn);
                pd = fmaf(cwp[j], uu, pd);
            }
            pn += __int_as_float(__builtin_amdgcn_ds_bpermute(pidx, __float_as_int(pn)));
            pd += __int_as_float(__builtin_amdgcn_ds_bpermute(pidx, __float_as_int(pd)));
            float num = fmaf(cmt, v, gvl) + (pn + wnc);
            float den = den0 + pd + wdc;
            v = num * __builtin_amdgcn_rcpf(den);
        }
        if (l == 0 && tt >= s_out) out[tt] = fmaf(v, owv, obv);
        wnc = wnn; wdc = wdn;
    }
}

// ---------------------------------------------------------------------------
extern "C" void kernel_launch(void* const* d_in, const int* in_sizes, int n_in,
                              void* d_out, int out_size, void* d_ws, size_t ws_size,
                              hipStream_t stream) {
    const float* x      = (const float*)d_in[0];
    const float* conv_w = (const float*)d_in[1];
    const float* conv_b = (const float*)d_in[2];
    const float* fc1_w  = (const float*)d_in[3];
    const float* fc1_b  = (const float*)d_in[4];
    const float* fc2_w  = (const float*)d_in[5];
    const float* fc2_b  = (const float*)d_in[6];
    const float* iw     = (const float*)d_in[7];
    const float* ib     = (const float*)d_in[8];
    const float* sw     = (const float*)d_in[9];
    const float* smu    = (const float*)d_in[10];
    const float* ssig   = (const float*)d_in[11];
    const float* serev  = (const float*)d_in[12];
    const float* smask  = (const float*)d_in[13];
    const float* w      = (const float*)d_in[14];
    const float* mu     = (const float*)d_in[15];
    const float* sigma  = (const float*)d_in[16];
    const float* erev   = (const float*)d_in[17];
    const float* mask   = (const float*)d_in[18];
    const float* gleak  = (const float*)d_in[19];
    const float* vleak  = (const float*)d_in[20];
    const float* cm     = (const float*)d_in[21];
    const float* ow     = (const float*)d_in[22];
    const float* ob     = (const float*)d_in[23];

    // ws layout — total 315,584 floats = 1,262,336 bytes. Never grow past
    // ws_size: a 3.36 MB layout corrupted neighboring allocations in R0.
    float* ws   = (float*)d_ws;
    float* wn_s = ws;                    // 8192*19 = 155648
    float* wd_s = wn_s + 155648;         // 155648
    float* sc1  = wd_s + 155648;         // 640 each
    float* sc0  = sc1 + 640;
    float* swe  = sc0 + 640;
    float* swp  = swe + 640;
    float* rc1  = swp + 640;             // 384 each
    float* rc0  = rc1 + 384;
    float* rwe  = rc0 + 384;
    float* rwp  = rwe + 384;
    float* neu  = rwp + 384;             // 192
    (void)ws_size; (void)in_sizes; (void)n_in; (void)out_size;

    hipLaunchKernelGGL(k0_precompute, dim3(1), dim3(640), 0, stream,
        sw, smu, ssig, serev, smask, w, mu, sigma, erev, mask,
        gleak, vleak, cm, sc1, sc0, swe, swp, rc1, rc0, rwe, rwp, neu);

    hipLaunchKernelGGL(k12_frontend, dim3(256), dim3(512), 0, stream,
        x, conv_w, conv_b, fc1_w, fc1_b, fc2_w, fc2_b, iw, ib,
        sc1, sc0, swe, swp, wn_s, wd_s);

    hipLaunchKernelGGL(k3p2_scan, dim3(SCAN_CHUNKS), dim3(64), 0, stream,
        wn_s, wd_s, rc1, rc0, rwe, rwp, neu, ow, ob, (float*)d_out);
}

// Round 6
// 545.101 us; speedup vs baseline: 2.3458x; 1.1475x over previous
//
#include <hip/hip_runtime.h>
#include <hip/hip_bf16.h>
#include <math.h>

#define L2E 1.4426950408889634f
#define T_STEPS 8192
#define KTOT 5104   // 8 channels * 638 spatial (22*29)
#define EPS_LTC 1e-8f

// scan chunking: 1024 chunks x 8 steps, 16-step burn-in (chunks 0,1 exact).
#define SCAN_CHUNKS 1024
#define S_PER  8
#define WARM   16

typedef __attribute__((ext_vector_type(8))) short bfrag;   // 8 bf16 (4 VGPR)
typedef __attribute__((ext_vector_type(4))) float ffrag;   // 4 fp32 acc

__device__ __forceinline__ float softplus_f(float x) {
    return log1pf(expf(-fabsf(x))) + fmaxf(x, 0.f);
}

__device__ __forceinline__ unsigned short bf_hi(float f) {  // RNE fp32->bf16
    unsigned u = __float_as_uint(f);
    u = u + 0x7FFFu + ((u >> 16) & 1u);
    return (unsigned short)(u >> 16);
}

// ---------------------------------------------------------------------------
// K0: parameter precompute (tiny).
// ---------------------------------------------------------------------------
__global__ void k0_precompute(
    const float* __restrict__ sw, const float* __restrict__ smu,
    const float* __restrict__ ssig, const float* __restrict__ serev,
    const float* __restrict__ smask,
    const float* __restrict__ w, const float* __restrict__ mu,
    const float* __restrict__ sigma, const float* __restrict__ erev,
    const float* __restrict__ mask,
    const float* __restrict__ gleak, const float* __restrict__ vleak,
    const float* __restrict__ cm,
    float* __restrict__ sc1, float* __restrict__ sc0,
    float* __restrict__ swe, float* __restrict__ swp,
    float* __restrict__ rc1, float* __restrict__ rc0,
    float* __restrict__ rwe, float* __restrict__ rwp,
    float* __restrict__ neu)
{
    int t = threadIdx.x;
    if (t < 608) {   // sensory (32 x 19)
        float sp = softplus_f(sw[t]);
        float c1 = ssig[t] * L2E;
        sc1[t] = c1;
        sc0[t] = c1 * smu[t];
        swe[t] = sp * serev[t];
        swp[t] = sp * smask[t];
    }
    if (t < 361) {   // recurrent (19 x 19), layout [src*19 + tgt]
        float wp = softplus_f(w[t]) * mask[t];
        float c1 = sigma[t] * L2E;
        rc1[t] = c1;
        rc0[t] = c1 * mu[t];
        rwe[t] = wp * erev[t];
        rwp[t] = wp;
    }
    if (t < 64) {
        if (t < 19) {
            float g   = softplus_f(gleak[t]);
            float cmt = softplus_f(cm[t]) * 6.f;   // ODE_UNFOLDS
            neu[t]       = cmt;
            neu[64 + t]  = g * vleak[t];
            neu[128 + t] = cmt + g + EPS_LTC;
        } else {
            neu[t] = 0.f; neu[64 + t] = 0.f; neu[128 + t] = 1.f;
        }
    }
}

// ---------------------------------------------------------------------------
// K12 v6: MFMA front-end. conv2x2+ELU -> split-bf16 (hi+lo) -> fc1 GEMM via
// mfma_f32_16x16x32_bf16 (3 products: yh*wh + yh*wl + yl*wh, err ~2^-18)
// -> ReLU -> hS in LDS -> fc2 + input affine -> sensory sums.
// Block: 32 samples x 64 outs, 512 thr = 8 waves = 8 (Mtile,Ntile) 16x16 tiles.
// K permuted channel-inner: j in [0,32): o=j&7, rr=j>>3, k = o*638 + kc*4+rr
// (same permutation for A and B => GEMM sum unchanged; keeps R3's FETCH win).
// ---------------------------------------------------------------------------
__global__ __launch_bounds__(512) void k12_frontend(
    const float* __restrict__ x, const float* __restrict__ conv_w,
    const float* __restrict__ conv_b,
    const float* __restrict__ fc1_w, const float* __restrict__ fc1_b,
    const float* __restrict__ fc2_w, const float* __restrict__ fc2_b,
    const float* __restrict__ iw, const float* __restrict__ ib,
    const float* __restrict__ sc1, const float* __restrict__ sc0,
    const float* __restrict__ swe, const float* __restrict__ swp,
    float* __restrict__ wn_s, float* __restrict__ wd_s)
{
    __shared__ __align__(16) float smem[5544];
    // During K-loop (ushort view): A_hi[0,1024) A_lo[1024,2048) B_hi[2048,4096) B_lo[4096,6144)
    unsigned short* AB = (unsigned short*)smem;
    unsigned* AB32 = (unsigned*)smem;
    // Post K-loop (float view):
    float* hS   = smem;            // 32 x 68 = 2176 f
    float* w2S  = smem + 2304;     // [s][n] stride 65, 2080 f
    float* seqS = smem + 4384;     // [sample][s] stride 33, 1056 f
    float* cwS  = smem + 5440;     // 96 (live through K-loop, beyond AB's 3072 f)
    float* cbS  = smem + 5536;     // 8

    const int t  = threadIdx.x;     // 0..511
    const int b0 = blockIdx.x * 32;
    if (t < 96) cwS[t] = conv_w[t];
    if (t < 8)  cbS[t] = conv_b[t];

    const int lane = t & 63;
    const int wv   = t >> 6;        // 0..7
    const int mt   = wv & 1;        // M-tile (samples 16*mt..)
    const int nt   = wv >> 1;       // N-tile (outs 16*nt..)
    const int q    = lane >> 4;     // quad
    const int mn   = lane & 15;

    // staging roles
    const int ym  = t & 31;         // y: sample row
    const int yj  = (t >> 5) * 2;   // y: j0 (even) -> channels yo,yo+1, same rr
    const int yo  = yj & 7;
    const int yrr = yj >> 3;
    const int wout = t >> 3;        // w: out row 0..63
    const int wj   = (t & 7) * 4;   // w: j0 in {0,4,..28} -> channels wo..wo+3, same rr
    const int wo   = wj & 7;
    const int wrr  = wj >> 3;

    const int aoff = (mt * 16 + mn) * 32 + q * 8;          // ushort idx, 16B-aligned
    const int boff = 2048 + (nt * 16 + mn) * 32 + q * 8;

    ffrag acc = {0.f, 0.f, 0.f, 0.f};
    __syncthreads();

    for (int kc = 0; kc < 160; kc++) {
        // ---- stage A (y): 2 conv+ELU values, split hi/lo bf16 ----
        {
            int r = kc * 4 + yrr;
            float y0 = 0.f, y1 = 0.f;
            if (r < 638) {
                int oh = r / 29, ow = r - oh * 29;
                const float* xp = x + (size_t)(b0 + ym) * 2070 + oh * 30 + ow;
                y0 = cbS[yo]; y1 = cbS[yo + 1];
                #pragma unroll
                for (int cc = 0; cc < 3; cc++) {
                    const float* xq = xp + cc * 690;
                    float x00 = xq[0], x01 = xq[1], x10 = xq[30], x11 = xq[31];
                    const float* w0 = cwS + yo * 12 + cc * 4;
                    const float* w1 = w0 + 12;
                    y0 = fmaf(x00, w0[0], y0); y0 = fmaf(x01, w0[1], y0);
                    y0 = fmaf(x10, w0[2], y0); y0 = fmaf(x11, w0[3], y0);
                    y1 = fmaf(x00, w1[0], y1); y1 = fmaf(x01, w1[1], y1);
                    y1 = fmaf(x10, w1[2], y1); y1 = fmaf(x11, w1[3], y1);
                }
                y0 = (y0 > 0.f) ? y0 : expm1f(y0);
                y1 = (y1 > 0.f) ? y1 : expm1f(y1);
            }
            unsigned short h0 = bf_hi(y0), h1 = bf_hi(y1);
            float l0 = y0 - __uint_as_float((unsigned)h0 << 16);
            float l1 = y1 - __uint_as_float((unsigned)h1 << 16);
            unsigned short g0 = bf_hi(l0), g1 = bf_hi(l1);
            AB32[(ym * 32 + yj) >> 1]          = (unsigned)h0 | ((unsigned)h1 << 16);
            AB32[(1024 + ym * 32 + yj) >> 1]   = (unsigned)g0 | ((unsigned)g1 << 16);
        }
        // ---- stage B (w): 4 fc1 weights, split hi/lo bf16 ----
        {
            int r = kc * 4 + wrr;
            float v0 = 0.f, v1 = 0.f, v2 = 0.f, v3 = 0.f;
            if (r < 638) {
                const float* wp = fc1_w + (size_t)wout * KTOT + wo * 638 + r;
                v0 = wp[0]; v1 = wp[638]; v2 = wp[1276]; v3 = wp[1914];
            }
            unsigned short a0 = bf_hi(v0), a1 = bf_hi(v1), a2 = bf_hi(v2), a3 = bf_hi(v3);
            float f0 = v0 - __uint_as_float((unsigned)a0 << 16);
            float f1 = v1 - __uint_as_float((unsigned)a1 << 16);
            float f2 = v2 - __uint_as_float((unsigned)a2 << 16);
            float f3 = v3 - __uint_as_float((unsigned)a3 << 16);
            unsigned short c0 = bf_hi(f0), c1 = bf_hi(f1), c2 = bf_hi(f2), c3 = bf_hi(f3);
            int dh = (2048 + wout * 32 + wj) >> 1;
            int dl = (4096 + wout * 32 + wj) >> 1;
            AB32[dh]     = (unsigned)a0 | ((unsigned)a1 << 16);
            AB32[dh + 1] = (unsigned)a2 | ((unsigned)a3 << 16);
            AB32[dl]     = (unsigned)c0 | ((unsigned)c1 << 16);
            AB32[dl + 1] = (unsigned)c2 | ((unsigned)c3 << 16);
        }
        __syncthreads();

        // ---- fragments + 3 MFMAs ----
        bfrag a_hi = *(const bfrag*)&AB[aoff];
        bfrag a_lo = *(const bfrag*)&AB[1024 + aoff];
        bfrag b_hi = *(const bfrag*)&AB[boff];
        bfrag b_lo = *(const bfrag*)&AB[2048 + boff];
        acc = __builtin_amdgcn_mfma_f32_16x16x32_bf16(a_hi, b_hi, acc, 0, 0, 0);
        acc = __builtin_amdgcn_mfma_f32_16x16x32_bf16(a_hi, b_lo, acc, 0, 0, 0);
        acc = __builtin_amdgcn_mfma_f32_16x16x32_bf16(a_lo, b_hi, acc, 0, 0, 0);
        __syncthreads();
    }

    // ---- epilogue: C/D (col=lane&15, row=quad*4+reg) -> hS with ReLU+bias ----
    {
        int n = nt * 16 + mn;
        float bn = fc1_b[n];
        #pragma unroll
        for (int rg = 0; rg < 4; rg++) {
            int m = mt * 16 + q * 4 + rg;
            hS[m * 68 + n] = fmaxf(acc[rg] + bn, 0.f);
        }
    }
    // ---- stage fc2 weights ----
    #pragma unroll
    for (int e = 0; e < 4; e++) {
        int flat = e * 512 + t;           // 2048 = 32*64
        int s = flat >> 6, n = flat & 63;
        w2S[s * 65 + n] = fc2_w[flat];
    }
    __syncthreads();

    // ---- fc2 + input affine -> seq (32 samples x 32 sensory) ----
    #pragma unroll
    for (int e = 0; e < 2; e++) {
        int flat = e * 512 + t;           // 1024 = 32*32
        int s = flat & 31, bl = flat >> 5;
        float a2 = fc2_b[s];
        #pragma unroll 8
        for (int n = 0; n < 64; n++)
            a2 = fmaf(hS[bl * 68 + n], w2S[s * 65 + n], a2);
        seqS[bl * 33 + s] = a2 * iw[s] + ib[s];
    }
    __syncthreads();

    // ---- sensory synapse sums (32 samples x 19 neurons = 608 items) ----
    #pragma unroll
    for (int e = 0; e < 2; e++) {
        int flat = e * 512 + t;
        if (flat < 608) {
            int n = flat % 19, bl = flat / 19;
            float wn = 0.f, wd = 0.f;
            #pragma unroll
            for (int s = 0; s < 32; s++) {
                float xx = sc0[s * 19 + n] - sc1[s * 19 + n] * seqS[bl * 33 + s];
                float ee = __builtin_amdgcn_exp2f(xx);
                float uu = __builtin_amdgcn_rcpf(1.f + ee);
                wn = fmaf(swe[s * 19 + n], uu, wn);
                wd = fmaf(swp[s * 19 + n], uu, wd);
            }
            wn_s[(b0 + bl) * 19 + n] = wn;
            wd_s[(b0 + bl) * 19 + n] = wd;
        }
    }
}

// ---------------------------------------------------------------------------
// K3P v3: chunk-parallel LTC scan, one wave per chunk — no barriers, no LDS.
// ---------------------------------------------------------------------------
__global__ __launch_bounds__(64, 1) void k3p2_scan(
    const float* __restrict__ wn_s, const float* __restrict__ wd_s,
    const float* __restrict__ rc1, const float* __restrict__ rc0,
    const float* __restrict__ rwe, const float* __restrict__ rwp,
    const float* __restrict__ neu,
    const float* __restrict__ out_w, const float* __restrict__ out_b,
    float* __restrict__ out)
{
    const int l    = threadIdx.x;       // 0..63
    const int col  = l & 31;            // target neuron (19 real + 13 pad)
    const int p    = l >> 5;            // source half
    const int cidx = (col < 19) ? col : 0;

    float ca[10], cb[10], cwe[10], cwp[10];
    int gidx[10];
    #pragma unroll
    for (int j = 0; j < 10; j++) {
        int s = p * 10 + j;
        bool e = (col < 19) && (s < 19);
        int idx = e ? (s * 19 + col) : 0;
        ca[j]  = e ? rc1[idx] : 0.f;
        cb[j]  = e ? rc0[idx] : 0.f;
        cwe[j] = e ? rwe[idx] : 0.f;
        cwp[j] = e ? rwp[idx] : 0.f;
        gidx[j] = ((s < 19) ? s : 0) * 4;
    }

    const float cmt  = neu[cidx];
    const float gvl  = neu[64 + cidx];
    const float den0 = neu[128 + cidx];
    const float owv  = out_w[0];
    const float obv  = out_b[0];

    const int c       = blockIdx.x;
    const int s_out   = c * S_PER;
    const int s_begin = (s_out > WARM) ? (s_out - WARM) : 0;
    const int s_end   = s_out + S_PER;
    const int pidx    = (l ^ 32) * 4;

    float v = 0.f;
    float wnc = wn_s[s_begin * 19 + cidx];
    float wdc = wd_s[s_begin * 19 + cidx];

    for (int tt = s_begin; tt < s_end; tt++) {
        int nt = (tt + 1 < T_STEPS) ? (tt + 1) : (T_STEPS - 1);
        float wnn = wn_s[nt * 19 + cidx];
        float wdn = wd_s[nt * 19 + cidx];

        #pragma unroll
        for (int u = 0; u < 6; u++) {
            float pn = 0.f, pd = 0.f;
            #pragma unroll
            for (int j = 0; j < 10; j++) {
                float vs = __int_as_float(
                    __builtin_amdgcn_ds_bpermute(gidx[j], __float_as_int(v)));
                float xx = cb[j] - ca[j] * vs;
                float ee = __builtin_amdgcn_exp2f(xx);
                float uu = __builtin_amdgcn_rcpf(1.f + ee);
                pn = fmaf(cwe[j], uu, pn);
                pd = fmaf(cwp[j], uu, pd);
            }
            pn += __int_as_float(__builtin_amdgcn_ds_bpermute(pidx, __float_as_int(pn)));
            pd += __int_as_float(__builtin_amdgcn_ds_bpermute(pidx, __float_as_int(pd)));
            float num = fmaf(cmt, v, gvl) + (pn + wnc);
            float den = den0 + pd + wdc;
            v = num * __builtin_amdgcn_rcpf(den);
        }
        if (l == 0 && tt >= s_out) out[tt] = fmaf(v, owv, obv);
        wnc = wnn; wdc = wdn;
    }
}

// ---------------------------------------------------------------------------
extern "C" void kernel_launch(void* const* d_in, const int* in_sizes, int n_in,
                              void* d_out, int out_size, void* d_ws, size_t ws_size,
                              hipStream_t stream) {
    const float* x      = (const float*)d_in[0];
    const float* conv_w = (const float*)d_in[1];
    const float* conv_b = (const float*)d_in[2];
    const float* fc1_w  = (const float*)d_in[3];
    const float* fc1_b  = (const float*)d_in[4];
    const float* fc2_w  = (const float*)d_in[5];
    const float* fc2_b  = (const float*)d_in[6];
    const float* iw     = (const float*)d_in[7];
    const float* ib     = (const float*)d_in[8];
    const float* sw     = (const float*)d_in[9];
    const float* smu    = (const float*)d_in[10];
    const float* ssig   = (const float*)d_in[11];
    const float* serev  = (const float*)d_in[12];
    const float* smask  = (const float*)d_in[13];
    const float* w      = (const float*)d_in[14];
    const float* mu     = (const float*)d_in[15];
    const float* sigma  = (const float*)d_in[16];
    const float* erev   = (const float*)d_in[17];
    const float* mask   = (const float*)d_in[18];
    const float* gleak  = (const float*)d_in[19];
    const float* vleak  = (const float*)d_in[20];
    const float* cm     = (const float*)d_in[21];
    const float* ow     = (const float*)d_in[22];
    const float* ob     = (const float*)d_in[23];

    // ws layout — total 315,584 floats = 1,262,336 bytes. Never grow past
    // ws_size: a 3.36 MB layout corrupted neighboring allocations in R0.
    float* ws   = (float*)d_ws;
    float* wn_s = ws;                    // 8192*19 = 155648
    float* wd_s = wn_s + 155648;         // 155648
    float* sc1  = wd_s + 155648;         // 640 each
    float* sc0  = sc1 + 640;
    float* swe  = sc0 + 640;
    float* swp  = swe + 640;
    float* rc1  = swp + 640;             // 384 each
    float* rc0  = rc1 + 384;
    float* rwe  = rc0 + 384;
    float* rwp  = rwe + 384;
    float* neu  = rwp + 384;             // 192
    (void)ws_size; (void)in_sizes; (void)n_in; (void)out_size;

    hipLaunchKernelGGL(k0_precompute, dim3(1), dim3(640), 0, stream,
        sw, smu, ssig, serev, smask, w, mu, sigma, erev, mask,
        gleak, vleak, cm, sc1, sc0, swe, swp, rc1, rc0, rwe, rwp, neu);

    hipLaunchKernelGGL(k12_frontend, dim3(256), dim3(512), 0, stream,
        x, conv_w, conv_b, fc1_w, fc1_b, fc2_w, fc2_b, iw, ib,
        sc1, sc0, swe, swp, wn_s, wd_s);

    hipLaunchKernelGGL(k3p2_scan, dim3(SCAN_CHUNKS), dim3(64), 0, stream,
        wn_s, wd_s, rc1, rc0, rwe, rwp, neu, ow, ob, (float*)d_out);
}

// Round 7
// 491.253 us; speedup vs baseline: 2.6029x; 1.1096x over previous
//
#include <hip/hip_runtime.h>
#include <hip/hip_bf16.h>
#include <math.h>

#define L2E 1.4426950408889634f
#define T_STEPS 8192
#define KTOT 5104   // 8 channels * 638 spatial (22*29)
#define EPS_LTC 1e-8f

// scan chunking: 1024 chunks x 8 steps, 16-step burn-in (chunks 0,1 exact).
#define SCAN_CHUNKS 1024
#define S_PER  8
#define WARM   16

typedef __attribute__((ext_vector_type(8))) short bfrag;   // 8 bf16 (4 VGPR)
typedef __attribute__((ext_vector_type(4))) float ffrag;   // 4 fp32 acc

__device__ __forceinline__ float softplus_f(float x) {
    return log1pf(expf(-fabsf(x))) + fmaxf(x, 0.f);
}

__device__ __forceinline__ unsigned short bf_hi(float f) {  // RNE fp32->bf16
    unsigned u = __float_as_uint(f);
    u = u + 0x7FFFu + ((u >> 16) & 1u);
    return (unsigned short)(u >> 16);
}

// ---------------------------------------------------------------------------
// K0: parameter precompute (tiny).
// ---------------------------------------------------------------------------
__global__ void k0_precompute(
    const float* __restrict__ sw, const float* __restrict__ smu,
    const float* __restrict__ ssig, const float* __restrict__ serev,
    const float* __restrict__ smask,
    const float* __restrict__ w, const float* __restrict__ mu,
    const float* __restrict__ sigma, const float* __restrict__ erev,
    const float* __restrict__ mask,
    const float* __restrict__ gleak, const float* __restrict__ vleak,
    const float* __restrict__ cm,
    float* __restrict__ sc1, float* __restrict__ sc0,
    float* __restrict__ swe, float* __restrict__ swp,
    float* __restrict__ rc1, float* __restrict__ rc0,
    float* __restrict__ rwe, float* __restrict__ rwp,
    float* __restrict__ neu)
{
    int t = threadIdx.x;
    if (t < 608) {   // sensory (32 x 19)
        float sp = softplus_f(sw[t]);
        float c1 = ssig[t] * L2E;
        sc1[t] = c1;
        sc0[t] = c1 * smu[t];
        swe[t] = sp * serev[t];
        swp[t] = sp * smask[t];
    }
    if (t < 361) {   // recurrent (19 x 19), layout [src*19 + tgt]
        float wp = softplus_f(w[t]) * mask[t];
        float c1 = sigma[t] * L2E;
        rc1[t] = c1;
        rc0[t] = c1 * mu[t];
        rwe[t] = wp * erev[t];
        rwp[t] = wp;
    }
    if (t < 64) {
        if (t < 19) {
            float g   = softplus_f(gleak[t]);
            float cmt = softplus_f(cm[t]) * 6.f;   // ODE_UNFOLDS
            neu[t]       = cmt;
            neu[64 + t]  = g * vleak[t];
            neu[128 + t] = cmt + g + EPS_LTC;
        } else {
            neu[t] = 0.f; neu[64 + t] = 0.f; neu[128 + t] = 1.f;
        }
    }
}

// ---------------------------------------------------------------------------
// K12 v7: MFMA front-end, coalesced staging, 2 blocks/CU.
//  - 512 blocks x 256 thr: 16 samples x 64 outs, 4 waves = 4 N-tiles (M=16).
//  - K-chunk of 32 per kc, permutation j -> k = (j>>2)*638 + kc*4 + (j&3)
//    (applied to BOTH A and B => GEMM sum unchanged).
//  - A staging: thread (m=t>>4, jp=t&15): rr=jp&3, channels o0=2*(jp>>2),o0+1;
//    12 shared x loads -> 2 conv+ELU outputs; lanes sweep (rr,o) => x
//    addresses within a wave span only 4 m x 4 r windows (coalesced, vs 64
//    scattered lines in v6 which made staging TA-bound at ~5400 cyc/kc).
//  - B staging: thread (n=t>>2, jp=t&3): j0=8*jp -> two runs of 4 CONTIGUOUS
//    fc1_w floats; hi/lo packed into single 16B LDS stores.
// ---------------------------------------------------------------------------
__global__ __launch_bounds__(256) void k12_frontend(
    const float* __restrict__ x, const float* __restrict__ conv_w,
    const float* __restrict__ conv_b,
    const float* __restrict__ fc1_w, const float* __restrict__ fc1_b,
    const float* __restrict__ fc2_w, const float* __restrict__ fc2_b,
    const float* __restrict__ iw, const float* __restrict__ ib,
    const float* __restrict__ sc1, const float* __restrict__ sc0,
    const float* __restrict__ swe, const float* __restrict__ swp,
    float* __restrict__ wn_s, float* __restrict__ wd_s)
{
    __shared__ __align__(16) float smem[3832];
    // K-loop (ushort view): A_hi[0,512) A_lo[512,1024) B_hi[1024,3072) B_lo[3072,5120)
    unsigned short* AB = (unsigned short*)smem;
    uint4* AB128 = (uint4*)smem;
    // Post K-loop (float view):
    float* hS   = smem;            // 16 x 68 = 1088 f
    float* w2S  = smem + 1120;     // [s][n] stride 65, 2080 f
    float* seqS = smem + 3200;     // [sample][s] stride 33, 528 f
    float* cwS  = smem + 3728;     // 96  (beyond AB's 2560 f -> live through K-loop)
    float* cbS  = smem + 3824;     // 8

    const int t  = threadIdx.x;     // 0..255
    const int b0 = blockIdx.x * 16;
    if (t < 96) cwS[t] = conv_w[t];
    if (t < 8)  cbS[t] = conv_b[t];

    const int lane = t & 63;
    const int nt   = t >> 6;        // wave = N-tile 0..3
    const int q    = lane >> 4;     // quad
    const int mn   = lane & 15;

    // A staging role
    const int am  = t >> 4;         // sample 0..15
    const int ajp = t & 15;
    const int arr = ajp & 3;        // spatial offset in chunk
    const int ao0 = (ajp >> 2) * 2; // channels ao0, ao0+1
    // B staging role
    const int bn  = t >> 2;         // out 0..63
    const int bj0 = (t & 3) * 8;    // j0: channels 2*(t&3), 2*(t&3)+1
    const int bo0 = (t & 3) * 2;

    const int aoff = mn * 32 + q * 8;                   // A frag (ushort idx)
    const int boff = 1024 + (nt * 16 + mn) * 32 + q * 8;

    ffrag acc = {0.f, 0.f, 0.f, 0.f};
    __syncthreads();

    for (int kc = 0; kc < 160; kc++) {
        // ---- stage A: conv+ELU for (am, ao0/ao0+1, r=kc*4+arr), split bf16 ----
        {
            int r = kc * 4 + arr;
            float y0 = 0.f, y1 = 0.f;
            if (r < 638) {
                int oh = r / 29, ow = r - oh * 29;
                const float* xp = x + (size_t)(b0 + am) * 2070 + oh * 30 + ow;
                y0 = cbS[ao0]; y1 = cbS[ao0 + 1];
                #pragma unroll
                for (int cc = 0; cc < 3; cc++) {
                    const float* xq = xp + cc * 690;
                    float x00 = xq[0], x01 = xq[1], x10 = xq[30], x11 = xq[31];
                    const float* w0 = cwS + ao0 * 12 + cc * 4;
                    const float* w1 = w0 + 12;
                    y0 = fmaf(x00, w0[0], y0); y0 = fmaf(x01, w0[1], y0);
                    y0 = fmaf(x10, w0[2], y0); y0 = fmaf(x11, w0[3], y0);
                    y1 = fmaf(x00, w1[0], y1); y1 = fmaf(x01, w1[1], y1);
                    y1 = fmaf(x10, w1[2], y1); y1 = fmaf(x11, w1[3], y1);
                }
                y0 = (y0 > 0.f) ? y0 : expm1f(y0);
                y1 = (y1 > 0.f) ? y1 : expm1f(y1);
            }
            unsigned short h0 = bf_hi(y0), h1 = bf_hi(y1);
            float l0 = y0 - __uint_as_float((unsigned)h0 << 16);
            float l1 = y1 - __uint_as_float((unsigned)h1 << 16);
            int j0 = ao0 * 4 + arr;
            AB[am * 32 + j0]           = h0;
            AB[am * 32 + j0 + 4]       = h1;
            AB[512 + am * 32 + j0]     = bf_hi(l0);
            AB[512 + am * 32 + j0 + 4] = bf_hi(l1);
        }
        // ---- stage B: 8 fc1 weights (2 contiguous runs of 4), split bf16 ----
        {
            float v[8];
            const float* wp0 = fc1_w + (size_t)bn * KTOT + bo0 * 638 + kc * 4;
            const float* wp1 = wp0 + 638;
            if (kc < 159) {
                float2 p0 = *(const float2*)(wp0);
                float2 p1 = *(const float2*)(wp0 + 2);
                float2 p2 = *(const float2*)(wp1);
                float2 p3 = *(const float2*)(wp1 + 2);
                v[0] = p0.x; v[1] = p0.y; v[2] = p1.x; v[3] = p1.y;
                v[4] = p2.x; v[5] = p2.y; v[6] = p3.x; v[7] = p3.y;
            } else {
                #pragma unroll
                for (int c = 0; c < 4; c++) {
                    bool ok = (636 + c) < 638;   // kc*4+c < 638 at kc=159
                    v[c]     = ok ? wp0[c] : 0.f;
                    v[4 + c] = ok ? wp1[c] : 0.f;
                }
            }
            unsigned hi[4], lo[4];
            #pragma unroll
            for (int c = 0; c < 4; c++) {
                unsigned short ha = bf_hi(v[2 * c]), hb = bf_hi(v[2 * c + 1]);
                float la = v[2 * c]     - __uint_as_float((unsigned)ha << 16);
                float lb = v[2 * c + 1] - __uint_as_float((unsigned)hb << 16);
                hi[c] = (unsigned)ha | ((unsigned)hb << 16);
                lo[c] = (unsigned)bf_hi(la) | ((unsigned)bf_hi(lb) << 16);
            }
            int dh = (1024 + bn * 32 + bj0) >> 3;   // uint4 index (16B-aligned)
            int dl = (3072 + bn * 32 + bj0) >> 3;
            AB128[dh] = make_uint4(hi[0], hi[1], hi[2], hi[3]);
            AB128[dl] = make_uint4(lo[0], lo[1], lo[2], lo[3]);
        }
        __syncthreads();

        // ---- fragments + 3 MFMAs (yh*wh + yh*wl + yl*wh) ----
        bfrag a_hi = *(const bfrag*)&AB[aoff];
        bfrag a_lo = *(const bfrag*)&AB[512 + aoff];
        bfrag b_hi = *(const bfrag*)&AB[boff];
        bfrag b_lo = *(const bfrag*)&AB[2048 + boff];
        acc = __builtin_amdgcn_mfma_f32_16x16x32_bf16(a_hi, b_hi, acc, 0, 0, 0);
        acc = __builtin_amdgcn_mfma_f32_16x16x32_bf16(a_hi, b_lo, acc, 0, 0, 0);
        acc = __builtin_amdgcn_mfma_f32_16x16x32_bf16(a_lo, b_hi, acc, 0, 0, 0);
        __syncthreads();
    }

    // ---- epilogue: C/D (col=lane&15 -> n, row=quad*4+reg -> m) ----
    {
        int n = nt * 16 + mn;
        float bnv = fc1_b[n];
        #pragma unroll
        for (int rg = 0; rg < 4; rg++) {
            int m = q * 4 + rg;
            hS[m * 68 + n] = fmaxf(acc[rg] + bnv, 0.f);
        }
    }
    // ---- stage fc2 weights ----
    #pragma unroll
    for (int e = 0; e < 8; e++) {
        int flat = e * 256 + t;           // 2048 = 32*64
        int s = flat >> 6, n = flat & 63;
        w2S[s * 65 + n] = fc2_w[flat];
    }
    __syncthreads();

    // ---- fc2 + input affine -> seq (16 samples x 32 sensory) ----
    #pragma unroll
    for (int e = 0; e < 2; e++) {
        int flat = e * 256 + t;           // 512 = 16*32
        int s = flat & 31, bl = flat >> 5;
        float a2 = fc2_b[s];
        #pragma unroll 8
        for (int n = 0; n < 64; n++)
            a2 = fmaf(hS[bl * 68 + n], w2S[s * 65 + n], a2);
        seqS[bl * 33 + s] = a2 * iw[s] + ib[s];
    }
    __syncthreads();

    // ---- sensory synapse sums (16 samples x 19 neurons = 304 items) ----
    #pragma unroll
    for (int e = 0; e < 2; e++) {
        int flat = e * 256 + t;
        if (flat < 304) {
            int n = flat % 19, bl = flat / 19;
            float wn = 0.f, wd = 0.f;
            #pragma unroll
            for (int s = 0; s < 32; s++) {
                float xx = sc0[s * 19 + n] - sc1[s * 19 + n] * seqS[bl * 33 + s];
                float ee = __builtin_amdgcn_exp2f(xx);
                float uu = __builtin_amdgcn_rcpf(1.f + ee);
                wn = fmaf(swe[s * 19 + n], uu, wn);
                wd = fmaf(swp[s * 19 + n], uu, wd);
            }
            wn_s[(b0 + bl) * 19 + n] = wn;
            wd_s[(b0 + bl) * 19 + n] = wd;
        }
    }
}

// ---------------------------------------------------------------------------
// K3P v3: chunk-parallel LTC scan, one wave per chunk — no barriers, no LDS.
// ---------------------------------------------------------------------------
__global__ __launch_bounds__(64, 1) void k3p2_scan(
    const float* __restrict__ wn_s, const float* __restrict__ wd_s,
    const float* __restrict__ rc1, const float* __restrict__ rc0,
    const float* __restrict__ rwe, const float* __restrict__ rwp,
    const float* __restrict__ neu,
    const float* __restrict__ out_w, const float* __restrict__ out_b,
    float* __restrict__ out)
{
    const int l    = threadIdx.x;       // 0..63
    const int col  = l & 31;            // target neuron (19 real + 13 pad)
    const int p    = l >> 5;            // source half
    const int cidx = (col < 19) ? col : 0;

    float ca[10], cb[10], cwe[10], cwp[10];
    int gidx[10];
    #pragma unroll
    for (int j = 0; j < 10; j++) {
        int s = p * 10 + j;
        bool e = (col < 19) && (s < 19);
        int idx = e ? (s * 19 + col) : 0;
        ca[j]  = e ? rc1[idx] : 0.f;
        cb[j]  = e ? rc0[idx] : 0.f;
        cwe[j] = e ? rwe[idx] : 0.f;
        cwp[j] = e ? rwp[idx] : 0.f;
        gidx[j] = ((s < 19) ? s : 0) * 4;
    }

    const float cmt  = neu[cidx];
    const float gvl  = neu[64 + cidx];
    const float den0 = neu[128 + cidx];
    const float owv  = out_w[0];
    const float obv  = out_b[0];

    const int c       = blockIdx.x;
    const int s_out   = c * S_PER;
    const int s_begin = (s_out > WARM) ? (s_out - WARM) : 0;
    const int s_end   = s_out + S_PER;
    const int pidx    = (l ^ 32) * 4;

    float v = 0.f;
    float wnc = wn_s[s_begin * 19 + cidx];
    float wdc = wd_s[s_begin * 19 + cidx];

    for (int tt = s_begin; tt < s_end; tt++) {
        int nt = (tt + 1 < T_STEPS) ? (tt + 1) : (T_STEPS - 1);
        float wnn = wn_s[nt * 19 + cidx];
        float wdn = wd_s[nt * 19 + cidx];

        #pragma unroll
        for (int u = 0; u < 6; u++) {
            float pn = 0.f, pd = 0.f;
            #pragma unroll
            for (int j = 0; j < 10; j++) {
                float vs = __int_as_float(
                    __builtin_amdgcn_ds_bpermute(gidx[j], __float_as_int(v)));
                float xx = cb[j] - ca[j] * vs;
                float ee = __builtin_amdgcn_exp2f(xx);
                float uu = __builtin_amdgcn_rcpf(1.f + ee);
                pn = fmaf(cwe[j], uu, pn);
                pd = fmaf(cwp[j], uu, pd);
            }
            pn += __int_as_float(__builtin_amdgcn_ds_bpermute(pidx, __float_as_int(pn)));
            pd += __int_as_float(__builtin_amdgcn_ds_bpermute(pidx, __float_as_int(pd)));
            float num = fmaf(cmt, v, gvl) + (pn + wnc);
            float den = den0 + pd + wdc;
            v = num * __builtin_amdgcn_rcpf(den);
        }
        if (l == 0 && tt >= s_out) out[tt] = fmaf(v, owv, obv);
        wnc = wnn; wdc = wdn;
    }
}

// ---------------------------------------------------------------------------
extern "C" void kernel_launch(void* const* d_in, const int* in_sizes, int n_in,
                              void* d_out, int out_size, void* d_ws, size_t ws_size,
                              hipStream_t stream) {
    const float* x      = (const float*)d_in[0];
    const float* conv_w = (const float*)d_in[1];
    const float* conv_b = (const float*)d_in[2];
    const float* fc1_w  = (const float*)d_in[3];
    const float* fc1_b  = (const float*)d_in[4];
    const float* fc2_w  = (const float*)d_in[5];
    const float* fc2_b  = (const float*)d_in[6];
    const float* iw     = (const float*)d_in[7];
    const float* ib     = (const float*)d_in[8];
    const float* sw     = (const float*)d_in[9];
    const float* smu    = (const float*)d_in[10];
    const float* ssig   = (const float*)d_in[11];
    const float* serev  = (const float*)d_in[12];
    const float* smask  = (const float*)d_in[13];
    const float* w      = (const float*)d_in[14];
    const float* mu     = (const float*)d_in[15];
    const float* sigma  = (const float*)d_in[16];
    const float* erev   = (const float*)d_in[17];
    const float* mask   = (const float*)d_in[18];
    const float* gleak  = (const float*)d_in[19];
    const float* vleak  = (const float*)d_in[20];
    const float* cm     = (const float*)d_in[21];
    const float* ow     = (const float*)d_in[22];
    const float* ob     = (const float*)d_in[23];

    // ws layout — total 315,584 floats = 1,262,336 bytes. Never grow past
    // ws_size: a 3.36 MB layout corrupted neighboring allocations in R0.
    float* ws   = (float*)d_ws;
    float* wn_s = ws;                    // 8192*19 = 155648
    float* wd_s = wn_s + 155648;         // 155648
    float* sc1  = wd_s + 155648;         // 640 each
    float* sc0  = sc1 + 640;
    float* swe  = sc0 + 640;
    float* swp  = swe + 640;
    float* rc1  = swp + 640;             // 384 each
    float* rc0  = rc1 + 384;
    float* rwe  = rc0 + 384;
    float* rwp  = rwe + 384;
    float* neu  = rwp + 384;             // 192
    (void)ws_size; (void)in_sizes; (void)n_in; (void)out_size;

    hipLaunchKernelGGL(k0_precompute, dim3(1), dim3(640), 0, stream,
        sw, smu, ssig, serev, smask, w, mu, sigma, erev, mask,
        gleak, vleak, cm, sc1, sc0, swe, swp, rc1, rc0, rwe, rwp, neu);

    hipLaunchKernelGGL(k12_frontend, dim3(512), dim3(256), 0, stream,
        x, conv_w, conv_b, fc1_w, fc1_b, fc2_w, fc2_b, iw, ib,
        sc1, sc0, swe, swp, wn_s, wd_s);

    hipLaunchKernelGGL(k3p2_scan, dim3(SCAN_CHUNKS), dim3(64), 0, stream,
        wn_s, wd_s, rc1, rc0, rwe, rwp, neu, ow, ob, (float*)d_out);
}

// Round 8
// 482.200 us; speedup vs baseline: 2.6518x; 1.0188x over previous
//
#include <hip/hip_runtime.h>
#include <hip/hip_bf16.h>
#include <math.h>

#define L2E 1.4426950408889634f
#define T_STEPS 8192
#define KTOT 5104   // 8 channels * 638 spatial (22*29)
#define EPS_LTC 1e-8f
#define KP 5120     // permuted/padded K (160 chunks x 32)

// scan chunking: 1024 chunks x 8 steps, 16-step burn-in (chunks 0,1 exact).
#define SCAN_CHUNKS 1024
#define S_PER  8
#define WARM   16

// ws layout (floats): base 315,584 f = 1,262,336 B; optional pre-split B adds
// 2 x 327,680 ushorts = 1,310,720 B  ->  total 2,573,056 B (gated on ws_size).
#define WS_BASE_FLOATS 315584
#define WS_NEED_BSP    2573056

typedef __attribute__((ext_vector_type(8))) short bfrag;   // 8 bf16 (4 VGPR)
typedef __attribute__((ext_vector_type(4))) float ffrag;   // 4 fp32 acc

__device__ __forceinline__ float softplus_f(float x) {
    return log1pf(expf(-fabsf(x))) + fmaxf(x, 0.f);
}

__device__ __forceinline__ unsigned short bf_hi(float f) {  // RNE fp32->bf16
    unsigned u = __float_as_uint(f);
    u = u + 0x7FFFu + ((u >> 16) & 1u);
    return (unsigned short)(u >> 16);
}

// ---------------------------------------------------------------------------
// K0: parameter precompute (tiny).
// ---------------------------------------------------------------------------
__global__ void k0_precompute(
    const float* __restrict__ sw, const float* __restrict__ smu,
    const float* __restrict__ ssig, const float* __restrict__ serev,
    const float* __restrict__ smask,
    const float* __restrict__ w, const float* __restrict__ mu,
    const float* __restrict__ sigma, const float* __restrict__ erev,
    const float* __restrict__ mask,
    const float* __restrict__ gleak, const float* __restrict__ vleak,
    const float* __restrict__ cm,
    float* __restrict__ sc1, float* __restrict__ sc0,
    float* __restrict__ swe, float* __restrict__ swp,
    float* __restrict__ rc1, float* __restrict__ rc0,
    float* __restrict__ rwe, float* __restrict__ rwp,
    float* __restrict__ neu)
{
    int t = threadIdx.x;
    if (t < 608) {   // sensory (32 x 19)
        float sp = softplus_f(sw[t]);
        float c1 = ssig[t] * L2E;
        sc1[t] = c1;
        sc0[t] = c1 * smu[t];
        swe[t] = sp * serev[t];
        swp[t] = sp * smask[t];
    }
    if (t < 361) {   // recurrent (19 x 19), layout [src*19 + tgt]
        float wp = softplus_f(w[t]) * mask[t];
        float c1 = sigma[t] * L2E;
        rc1[t] = c1;
        rc0[t] = c1 * mu[t];
        rwe[t] = wp * erev[t];
        rwp[t] = wp;
    }
    if (t < 64) {
        if (t < 19) {
            float g   = softplus_f(gleak[t]);
            float cmt = softplus_f(cm[t]) * 6.f;   // ODE_UNFOLDS
            neu[t]       = cmt;
            neu[64 + t]  = g * vleak[t];
            neu[128 + t] = cmt + g + EPS_LTC;
        } else {
            neu[t] = 0.f; neu[64 + t] = 0.f; neu[128 + t] = 1.f;
        }
    }
}

// ---------------------------------------------------------------------------
// K0B: pre-split fc1_w into bf16 hi/lo in PERMUTED fragment order:
// bhi[n*KP + kc*32 + idx], idx -> (o = idx>>2, rr = idx&3), k = o*638 + kc*4+rr.
// Lane (q,mn) of k12 then loads its whole B fragment as one 16B read. Runs
// every call (ws is re-poisoned); only launched when ws_size permits.
// ---------------------------------------------------------------------------
__global__ __launch_bounds__(256) void k0b_splitB(
    const float* __restrict__ fc1_w,
    unsigned short* __restrict__ bhi, unsigned short* __restrict__ blo)
{
    int g = blockIdx.x * 256 + threadIdx.x;   // 0 .. 64*5120-1
    int n  = g / KP;
    int kp = g - n * KP;
    int kc = kp >> 5, idx = kp & 31;
    int o = idx >> 2, rr = idx & 3;
    int r = kc * 4 + rr;
    float v = (r < 638) ? fc1_w[n * KTOT + o * 638 + r] : 0.f;
    unsigned short h = bf_hi(v);
    bhi[g] = h;
    blo[g] = bf_hi(v - __uint_as_float((unsigned)h << 16));
}

// ---------------------------------------------------------------------------
// K12 v8: barrier-free register-MFMA front-end.
//  - 512 blocks x 256 thr; block = 16 samples x 64 outs; 4 waves K-SPLIT
//    (wave w: kc in [40w, 40w+40)) -> no inter-wave sync in the K-loop.
//  - A-fragment computed IN REGISTERS: lane (q, mn) owns sample mn, channels
//    2q/2q+1, spatial kc*4..+3 == exactly its MFMA A-frag (8 conv+ELU values).
//    Conv computed once globally; zero LDS staging, zero K-loop barriers.
//  - B-fragment: direct global 16B loads from pre-split bhi/blo (or fp32
//    load+split fallback when ws too small).
//  - Epilogue: 4 partial Cs reduced via LDS (2 barriers total), then
//    fc2 + input affine + sensory sums as before.
// ---------------------------------------------------------------------------
__global__ __launch_bounds__(256) void k12_frontend(
    const float* __restrict__ x, const float* __restrict__ conv_w,
    const float* __restrict__ conv_b,
    const float* __restrict__ fc1_w, const float* __restrict__ fc1_b,
    const float* __restrict__ fc2_w, const float* __restrict__ fc2_b,
    const float* __restrict__ iw, const float* __restrict__ ib,
    const float* __restrict__ sc1, const float* __restrict__ sc0,
    const float* __restrict__ swe, const float* __restrict__ swp,
    const unsigned short* __restrict__ bhi,
    const unsigned short* __restrict__ blo, int use_bsp,
    float* __restrict__ wn_s, float* __restrict__ wd_s)
{
    __shared__ __align__(16) float smem[7792];
    float* redS = smem;            // [4][16][64] = 4096 f partial-C buffer
    float* hS   = smem + 4096;     // 16 x 68 = 1088 f
    float* w2S  = smem + 5184;     // [s][n] stride 65, 2080 f
    float* seqS = smem + 7264;     // [sample][s] stride 33, 528 f

    const int t    = threadIdx.x;   // 0..255
    const int b0   = blockIdx.x * 16;
    const int lane = t & 63;
    const int wv   = t >> 6;        // wave -> K quarter
    const int q    = lane >> 4;     // quad -> channel pair 2q,2q+1 / k-range
    const int mn   = lane & 15;     // sample (A) / out-within-tile (B)
    const int o0   = 2 * q;

    // conv weights + bias for this lane's channel pair, in registers
    float cw0[12], cw1[12];
    #pragma unroll
    for (int i = 0; i < 12; i++) {
        cw0[i] = conv_w[o0 * 12 + i];
        cw1[i] = conv_w[o0 * 12 + 12 + i];
    }
    const float cb0 = conv_b[o0], cb1 = conv_b[o0 + 1];
    const float* xbase = x + (size_t)(b0 + mn) * 2070;

    ffrag acc[4];
    #pragma unroll
    for (int nt = 0; nt < 4; nt++) acc[nt] = (ffrag){0.f, 0.f, 0.f, 0.f};

    const int kc0 = wv * 40;
    for (int kk = 0; kk < 40; kk++) {
        const int kc = kc0 + kk;
        // ---- conv + ELU: 8 outputs (2 ch x 4 spatial), all in registers ----
        float y0[4], y1[4];
        #pragma unroll
        for (int rr = 0; rr < 4; rr++) {
            int r = kc * 4 + rr;
            if (r < 638) {                        // wave-uniform (kc=159 only)
                int oh = (r * 565) >> 14;         // == r/29 for r<=637
                const float* xp = xbase + oh * 30 + (r - oh * 29);
                float a0 = cb0, a1 = cb1;
                #pragma unroll
                for (int cc = 0; cc < 3; cc++) {
                    float x00 = xp[cc * 690],      x01 = xp[cc * 690 + 1];
                    float x10 = xp[cc * 690 + 30], x11 = xp[cc * 690 + 31];
                    a0 = fmaf(x00, cw0[cc * 4 + 0], a0);
                    a0 = fmaf(x01, cw0[cc * 4 + 1], a0);
                    a0 = fmaf(x10, cw0[cc * 4 + 2], a0);
                    a0 = fmaf(x11, cw0[cc * 4 + 3], a0);
                    a1 = fmaf(x00, cw1[cc * 4 + 0], a1);
                    a1 = fmaf(x01, cw1[cc * 4 + 1], a1);
                    a1 = fmaf(x10, cw1[cc * 4 + 2], a1);
                    a1 = fmaf(x11, cw1[cc * 4 + 3], a1);
                }
                y0[rr] = (a0 > 0.f) ? a0 : expm1f(a0);
                y1[rr] = (a1 > 0.f) ? a1 : expm1f(a1);
            } else { y0[rr] = 0.f; y1[rr] = 0.f; }
        }
        // ---- build A hi/lo fragments (j=0..3 -> ch o0; j=4..7 -> ch o0+1) ----
        bfrag a_hi, a_lo;
        #pragma unroll
        for (int j = 0; j < 4; j++) {
            unsigned short h0 = bf_hi(y0[j]);
            a_hi[j] = (short)h0;
            a_lo[j] = (short)bf_hi(y0[j] - __uint_as_float((unsigned)h0 << 16));
            unsigned short h1 = bf_hi(y1[j]);
            a_hi[4 + j] = (short)h1;
            a_lo[4 + j] = (short)bf_hi(y1[j] - __uint_as_float((unsigned)h1 << 16));
        }
        // ---- B fragments + 3 MFMAs per N-tile ----
        if (use_bsp) {
            #pragma unroll
            for (int nt = 0; nt < 4; nt++) {
                int n = nt * 16 + mn;
                size_t off = (size_t)n * KP + kc * 32 + q * 8;
                bfrag b_h = *(const bfrag*)(bhi + off);
                bfrag b_l = *(const bfrag*)(blo + off);
                acc[nt] = __builtin_amdgcn_mfma_f32_16x16x32_bf16(a_hi, b_h, acc[nt], 0, 0, 0);
                acc[nt] = __builtin_amdgcn_mfma_f32_16x16x32_bf16(a_hi, b_l, acc[nt], 0, 0, 0);
                acc[nt] = __builtin_amdgcn_mfma_f32_16x16x32_bf16(a_lo, b_h, acc[nt], 0, 0, 0);
            }
        } else {
            #pragma unroll
            for (int nt = 0; nt < 4; nt++) {
                int n = nt * 16 + mn;
                bfrag b_h, b_l;
                #pragma unroll
                for (int j = 0; j < 8; j++) {
                    int o = o0 + (j >> 2);
                    int r = kc * 4 + (j & 3);
                    float vv = (r < 638) ? fc1_w[(size_t)n * KTOT + o * 638 + r] : 0.f;
                    unsigned short h = bf_hi(vv);
                    b_h[j] = (short)h;
                    b_l[j] = (short)bf_hi(vv - __uint_as_float((unsigned)h << 16));
                }
                acc[nt] = __builtin_amdgcn_mfma_f32_16x16x32_bf16(a_hi, b_h, acc[nt], 0, 0, 0);
                acc[nt] = __builtin_amdgcn_mfma_f32_16x16x32_bf16(a_hi, b_l, acc[nt], 0, 0, 0);
                acc[nt] = __builtin_amdgcn_mfma_f32_16x16x32_bf16(a_lo, b_h, acc[nt], 0, 0, 0);
            }
        }
    }

    // ---- cross-wave K reduction: partials -> LDS -> sum + bias + ReLU ----
    // C/D layout: col = lane&15 -> n-within-tile, row = q*4 + reg -> m.
    #pragma unroll
    for (int nt = 0; nt < 4; nt++) {
        int n = nt * 16 + mn;
        #pragma unroll
        for (int rg = 0; rg < 4; rg++) {
            int m = q * 4 + rg;
            redS[(wv * 16 + m) * 64 + n] = acc[nt][rg];
        }
    }
    __syncthreads();
    #pragma unroll
    for (int e = 0; e < 4; e++) {
        int flat = e * 256 + t;           // 1024 = 16*64
        int m = flat >> 6, n = flat & 63;
        float s = redS[m * 64 + n] + redS[(16 + m) * 64 + n]
                + redS[(32 + m) * 64 + n] + redS[(48 + m) * 64 + n];
        hS[m * 68 + n] = fmaxf(s + fc1_b[n], 0.f);
    }
    // ---- stage fc2 weights ----
    #pragma unroll
    for (int e = 0; e < 8; e++) {
        int flat = e * 256 + t;           // 2048 = 32*64
        int s = flat >> 6, n = flat & 63;
        w2S[s * 65 + n] = fc2_w[flat];
    }
    __syncthreads();

    // ---- fc2 + input affine -> seq (16 samples x 32 sensory) ----
    #pragma unroll
    for (int e = 0; e < 2; e++) {
        int flat = e * 256 + t;           // 512 = 16*32
        int s = flat & 31, bl = flat >> 5;
        float a2 = fc2_b[s];
        #pragma unroll 8
        for (int n = 0; n < 64; n++)
            a2 = fmaf(hS[bl * 68 + n], w2S[s * 65 + n], a2);
        seqS[bl * 33 + s] = a2 * iw[s] + ib[s];
    }
    __syncthreads();

    // ---- sensory synapse sums (16 samples x 19 neurons = 304 items) ----
    #pragma unroll
    for (int e = 0; e < 2; e++) {
        int flat = e * 256 + t;
        if (flat < 304) {
            int n = flat % 19, bl = flat / 19;
            float wn = 0.f, wd = 0.f;
            #pragma unroll
            for (int s = 0; s < 32; s++) {
                float xx = sc0[s * 19 + n] - sc1[s * 19 + n] * seqS[bl * 33 + s];
                float ee = __builtin_amdgcn_exp2f(xx);
                float uu = __builtin_amdgcn_rcpf(1.f + ee);
                wn = fmaf(swe[s * 19 + n], uu, wn);
                wd = fmaf(swp[s * 19 + n], uu, wd);
            }
            wn_s[(b0 + bl) * 19 + n] = wn;
            wd_s[(b0 + bl) * 19 + n] = wd;
        }
    }
}

// ---------------------------------------------------------------------------
// K3P v3: chunk-parallel LTC scan, one wave per chunk — UNCHANGED this round
// (isolating the k12 change; scan should surface in top-5 counters next).
// ---------------------------------------------------------------------------
__global__ __launch_bounds__(64, 1) void k3p2_scan(
    const float* __restrict__ wn_s, const float* __restrict__ wd_s,
    const float* __restrict__ rc1, const float* __restrict__ rc0,
    const float* __restrict__ rwe, const float* __restrict__ rwp,
    const float* __restrict__ neu,
    const float* __restrict__ out_w, const float* __restrict__ out_b,
    float* __restrict__ out)
{
    const int l    = threadIdx.x;       // 0..63
    const int col  = l & 31;            // target neuron (19 real + 13 pad)
    const int p    = l >> 5;            // source half
    const int cidx = (col < 19) ? col : 0;

    float ca[10], cb[10], cwe[10], cwp[10];
    int gidx[10];
    #pragma unroll
    for (int j = 0; j < 10; j++) {
        int s = p * 10 + j;
        bool e = (col < 19) && (s < 19);
        int idx = e ? (s * 19 + col) : 0;
        ca[j]  = e ? rc1[idx] : 0.f;
        cb[j]  = e ? rc0[idx] : 0.f;
        cwe[j] = e ? rwe[idx] : 0.f;
        cwp[j] = e ? rwp[idx] : 0.f;
        gidx[j] = ((s < 19) ? s : 0) * 4;
    }

    const float cmt  = neu[cidx];
    const float gvl  = neu[64 + cidx];
    const float den0 = neu[128 + cidx];
    const float owv  = out_w[0];
    const float obv  = out_b[0];

    const int c       = blockIdx.x;
    const int s_out   = c * S_PER;
    const int s_begin = (s_out > WARM) ? (s_out - WARM) : 0;
    const int s_end   = s_out + S_PER;
    const int pidx    = (l ^ 32) * 4;

    float v = 0.f;
    float wnc = wn_s[s_begin * 19 + cidx];
    float wdc = wd_s[s_begin * 19 + cidx];

    for (int tt = s_begin; tt < s_end; tt++) {
        int nt = (tt + 1 < T_STEPS) ? (tt + 1) : (T_STEPS - 1);
        float wnn = wn_s[nt * 19 + cidx];
        float wdn = wd_s[nt * 19 + cidx];

        #pragma unroll
        for (int u = 0; u < 6; u++) {
            float pn = 0.f, pd = 0.f;
            #pragma unroll
            for (int j = 0; j < 10; j++) {
                float vs = __int_as_float(
                    __builtin_amdgcn_ds_bpermute(gidx[j], __float_as_int(v)));
                float xx = cb[j] - ca[j] * vs;
                float ee = __builtin_amdgcn_exp2f(xx);
                float uu = __builtin_amdgcn_rcpf(1.f + ee);
                pn = fmaf(cwe[j], uu, pn);
                pd = fmaf(cwp[j], uu, pd);
            }
            pn += __int_as_float(__builtin_amdgcn_ds_bpermute(pidx, __float_as_int(pn)));
            pd += __int_as_float(__builtin_amdgcn_ds_bpermute(pidx, __float_as_int(pd)));
            float num = fmaf(cmt, v, gvl) + (pn + wnc);
            float den = den0 + pd + wdc;
            v = num * __builtin_amdgcn_rcpf(den);
        }
        if (l == 0 && tt >= s_out) out[tt] = fmaf(v, owv, obv);
        wnc = wnn; wdc = wdn;
    }
}

// ---------------------------------------------------------------------------
extern "C" void kernel_launch(void* const* d_in, const int* in_sizes, int n_in,
                              void* d_out, int out_size, void* d_ws, size_t ws_size,
                              hipStream_t stream) {
    const float* x      = (const float*)d_in[0];
    const float* conv_w = (const float*)d_in[1];
    const float* conv_b = (const float*)d_in[2];
    const float* fc1_w  = (const float*)d_in[3];
    const float* fc1_b  = (const float*)d_in[4];
    const float* fc2_w  = (const float*)d_in[5];
    const float* fc2_b  = (const float*)d_in[6];
    const float* iw     = (const float*)d_in[7];
    const float* ib     = (const float*)d_in[8];
    const float* sw     = (const float*)d_in[9];
    const float* smu    = (const float*)d_in[10];
    const float* ssig   = (const float*)d_in[11];
    const float* serev  = (const float*)d_in[12];
    const float* smask  = (const float*)d_in[13];
    const float* w      = (const float*)d_in[14];
    const float* mu     = (const float*)d_in[15];
    const float* sigma  = (const float*)d_in[16];
    const float* erev   = (const float*)d_in[17];
    const float* mask   = (const float*)d_in[18];
    const float* gleak  = (const float*)d_in[19];
    const float* vleak  = (const float*)d_in[20];
    const float* cm     = (const float*)d_in[21];
    const float* ow     = (const float*)d_in[22];
    const float* ob     = (const float*)d_in[23];

    float* ws   = (float*)d_ws;
    float* wn_s = ws;                    // 8192*19 = 155648
    float* wd_s = wn_s + 155648;         // 155648
    float* sc1  = wd_s + 155648;         // 640 each
    float* sc0  = sc1 + 640;
    float* swe  = sc0 + 640;
    float* swp  = swe + 640;
    float* rc1  = swp + 640;             // 384 each
    float* rc0  = rc1 + 384;
    float* rwe  = rc0 + 384;
    float* rwp  = rwe + 384;
    float* neu  = rwp + 384;             // 192  (base ends at 315,584 floats)
    // optional pre-split fc1_w (bf16 hi/lo), only if scratch is big enough
    const int use_bsp = (ws_size >= (size_t)WS_NEED_BSP) ? 1 : 0;
    unsigned short* bhi = (unsigned short*)(ws + WS_BASE_FLOATS);
    unsigned short* blo = bhi + 64 * KP;
    (void)in_sizes; (void)n_in; (void)out_size;

    hipLaunchKernelGGL(k0_precompute, dim3(1), dim3(640), 0, stream,
        sw, smu, ssig, serev, smask, w, mu, sigma, erev, mask,
        gleak, vleak, cm, sc1, sc0, swe, swp, rc1, rc0, rwe, rwp, neu);

    if (use_bsp) {
        hipLaunchKernelGGL(k0b_splitB, dim3(64 * KP / 256), dim3(256), 0, stream,
            fc1_w, bhi, blo);
    }

    hipLaunchKernelGGL(k12_frontend, dim3(512), dim3(256), 0, stream,
        x, conv_w, conv_b, fc1_w, fc1_b, fc2_w, fc2_b, iw, ib,
        sc1, sc0, swe, swp, bhi, blo, use_bsp, wn_s, wd_s);

    hipLaunchKernelGGL(k3p2_scan, dim3(SCAN_CHUNKS), dim3(64), 0, stream,
        wn_s, wd_s, rc1, rc0, rwe, rwp, neu, ow, ob, (float*)d_out);
}

// Round 9
// 367.292 us; speedup vs baseline: 3.4814x; 1.3129x over previous
//
#include <hip/hip_runtime.h>
#include <hip/hip_bf16.h>
#include <math.h>

#define L2E 1.4426950408889634f
#define T_STEPS 8192
#define KTOT 5104   // 8 channels * 638 spatial (22*29)
#define EPS_LTC 1e-8f
#define KP 5120     // permuted/padded K (160 chunks x 32)

// scan chunking: 1024 chunks x 8 steps, 16-step burn-in (chunks 0,1 exact).
#define SCAN_CHUNKS 1024
#define S_PER  8
#define WARM   16

// ws layout (floats): base 315,584 f = 1,262,336 B; optional pre-split B adds
// 2 x 327,680 ushorts = 1,310,720 B  ->  total 2,573,056 B (gated on ws_size).
#define WS_BASE_FLOATS 315584
#define WS_NEED_BSP    2573056

typedef __attribute__((ext_vector_type(8))) short bfrag;   // 8 bf16 (4 VGPR)
typedef __attribute__((ext_vector_type(4))) float ffrag;   // 4 fp32 acc
typedef __attribute__((ext_vector_type(4))) float fvec4;

__device__ __forceinline__ float softplus_f(float x) {
    return log1pf(expf(-fabsf(x))) + fmaxf(x, 0.f);
}

__device__ __forceinline__ unsigned short bf_hi(float f) {  // RNE fp32->bf16
    unsigned u = __float_as_uint(f);
    u = u + 0x7FFFu + ((u >> 16) & 1u);
    return (unsigned short)(u >> 16);
}

__device__ __forceinline__ float elu_f(float x) {
    return (x > 0.f) ? x : (__builtin_amdgcn_exp2f(x * L2E) - 1.f);
}

// ---------------------------------------------------------------------------
// K0: parameter precompute (tiny).
// ---------------------------------------------------------------------------
__global__ void k0_precompute(
    const float* __restrict__ sw, const float* __restrict__ smu,
    const float* __restrict__ ssig, const float* __restrict__ serev,
    const float* __restrict__ smask,
    const float* __restrict__ w, const float* __restrict__ mu,
    const float* __restrict__ sigma, const float* __restrict__ erev,
    const float* __restrict__ mask,
    const float* __restrict__ gleak, const float* __restrict__ vleak,
    const float* __restrict__ cm,
    float* __restrict__ sc1, float* __restrict__ sc0,
    float* __restrict__ swe, float* __restrict__ swp,
    float* __restrict__ rc1, float* __restrict__ rc0,
    float* __restrict__ rwe, float* __restrict__ rwp,
    float* __restrict__ neu)
{
    int t = threadIdx.x;
    if (t < 608) {   // sensory (32 x 19)
        float sp = softplus_f(sw[t]);
        float c1 = ssig[t] * L2E;
        sc1[t] = c1;
        sc0[t] = c1 * smu[t];
        swe[t] = sp * serev[t];
        swp[t] = sp * smask[t];
    }
    if (t < 361) {   // recurrent (19 x 19), layout [src*19 + tgt]
        float wp = softplus_f(w[t]) * mask[t];
        float c1 = sigma[t] * L2E;
        rc1[t] = c1;
        rc0[t] = c1 * mu[t];
        rwe[t] = wp * erev[t];
        rwp[t] = wp;
    }
    if (t < 64) {
        if (t < 19) {
            float g   = softplus_f(gleak[t]);
            float cmt = softplus_f(cm[t]) * 6.f;   // ODE_UNFOLDS
            neu[t]       = cmt;
            neu[64 + t]  = g * vleak[t];
            neu[128 + t] = cmt + g + EPS_LTC;
        } else {
            neu[t] = 0.f; neu[64 + t] = 0.f; neu[128 + t] = 1.f;
        }
    }
}

// ---------------------------------------------------------------------------
// K0B v2: pre-split fc1_w into bf16 hi/lo in FRAGMENT-INTERLEAVED order:
// offset g = (((kc*16 + q*4 + nt)*16) + mn)*8 + j
//   n = nt*16+mn ; o = 2q + (j>>2) ; r = kc*4 + (j&3) ; k = o*638 + r.
// A wave's per-(kc,nt) B-load is then 4x256B contiguous clusters (R8's
// n-major layout strided lanes 10 KB apart -> 500 MB HBM over-fetch).
// ---------------------------------------------------------------------------
__global__ __launch_bounds__(256) void k0b_splitB(
    const float* __restrict__ fc1_w,
    unsigned short* __restrict__ bhi, unsigned short* __restrict__ blo)
{
    int g = blockIdx.x * 256 + threadIdx.x;   // 0 .. 64*KP-1
    int j  = g & 7;
    int mn = (g >> 3) & 15;
    int nt = (g >> 7) & 3;
    int q  = (g >> 9) & 3;
    int kc = g >> 11;
    int n  = nt * 16 + mn;
    int o  = 2 * q + (j >> 2);
    int r  = kc * 4 + (j & 3);
    float v = (r < 638) ? fc1_w[n * KTOT + o * 638 + r] : 0.f;
    unsigned short h = bf_hi(v);
    bhi[g] = h;
    blo[g] = bf_hi(v - __uint_as_float((unsigned)h << 16));
}

// ---------------------------------------------------------------------------
// K12 v9: barrier-free register-MFMA front-end, L2-friendly B, vector conv.
//  - 512 blocks x 256 thr (launch_bounds(256,2)); 16 samples x 64 outs;
//    4 waves K-split (wave w: kc in [40w,40w+40)).
//  - B: 16B fragment loads from interleaved bhi/blo (contiguous per wave),
//    register double-buffered (kc+1 loaded before kc's MFMAs).
//  - A: conv+ELU in registers; fast path loads the shared 3ch x 2row x 5col
//    x-window with dwordx4 (12+6 instr vs 48 scalar).
// ---------------------------------------------------------------------------
__global__ __launch_bounds__(256, 2) void k12_frontend(
    const float* __restrict__ x, const float* __restrict__ conv_w,
    const float* __restrict__ conv_b,
    const float* __restrict__ fc1_w, const float* __restrict__ fc1_b,
    const float* __restrict__ fc2_w, const float* __restrict__ fc2_b,
    const float* __restrict__ iw, const float* __restrict__ ib,
    const float* __restrict__ sc1, const float* __restrict__ sc0,
    const float* __restrict__ swe, const float* __restrict__ swp,
    const unsigned short* __restrict__ bhi,
    const unsigned short* __restrict__ blo, int use_bsp,
    float* __restrict__ wn_s, float* __restrict__ wd_s)
{
    __shared__ __align__(16) float smem[7792];
    float* redS = smem;            // [4][16][64] = 4096 f partial-C buffer
    float* hS   = smem + 4096;     // 16 x 68 = 1088 f
    float* w2S  = smem + 5184;     // [s][n] stride 65, 2080 f
    float* seqS = smem + 7264;     // [sample][s] stride 33, 528 f

    const int t    = threadIdx.x;   // 0..255
    const int b0   = blockIdx.x * 16;
    const int lane = t & 63;
    const int wv   = t >> 6;        // wave -> K quarter
    const int q    = lane >> 4;     // quad -> channel pair 2q,2q+1
    const int mn   = lane & 15;     // sample (A) / out-within-tile (B)
    const int o0   = 2 * q;

    // conv weights + bias for this lane's channel pair, in registers
    float cw0[12], cw1[12];
    #pragma unroll
    for (int i = 0; i < 12; i++) {
        cw0[i] = conv_w[o0 * 12 + i];
        cw1[i] = conv_w[o0 * 12 + 12 + i];
    }
    const float cb0 = conv_b[o0], cb1 = conv_b[o0 + 1];
    const float* xbase = x + (size_t)(b0 + mn) * 2070;

    ffrag acc[4];
    #pragma unroll
    for (int nt = 0; nt < 4; nt++) acc[nt] = (ffrag){0.f, 0.f, 0.f, 0.f};

    const int kc0 = wv * 40;

    // conv+ELU -> split-bf16 A fragments for chunk kc (all in registers)
    auto convA = [&](int kc, bfrag& a_hi, bfrag& a_lo) {
        float y0[4], y1[4];
        int r0  = kc * 4;
        int oh0 = (r0 * 565) >> 14;          // == r0/29 for r0 <= 637
        int ow0 = r0 - oh0 * 29;
        if (ow0 <= 25 && r0 + 3 <= 637) {
            // fast path: all 4 positions in conv row oh0; shared 2x5 window
            float xr[3][2][5];
            #pragma unroll
            for (int cc = 0; cc < 3; cc++) {
                const float* a0 = xbase + cc * 690 + oh0 * 30 + ow0;
                fvec4 v0, v1;
                __builtin_memcpy(&v0, a0, 16);
                __builtin_memcpy(&v1, a0 + 30, 16);
                xr[cc][0][0] = v0.x; xr[cc][0][1] = v0.y;
                xr[cc][0][2] = v0.z; xr[cc][0][3] = v0.w;
                xr[cc][0][4] = a0[4];
                xr[cc][1][0] = v1.x; xr[cc][1][1] = v1.y;
                xr[cc][1][2] = v1.z; xr[cc][1][3] = v1.w;
                xr[cc][1][4] = a0[34];
            }
            #pragma unroll
            for (int rr = 0; rr < 4; rr++) {
                float a0v = cb0, a1v = cb1;
                #pragma unroll
                for (int cc = 0; cc < 3; cc++) {
                    float x00 = xr[cc][0][rr], x01 = xr[cc][0][rr + 1];
                    float x10 = xr[cc][1][rr], x11 = xr[cc][1][rr + 1];
                    a0v = fmaf(x00, cw0[cc * 4 + 0], a0v);
                    a0v = fmaf(x01, cw0[cc * 4 + 1], a0v);
                    a0v = fmaf(x10, cw0[cc * 4 + 2], a0v);
                    a0v = fmaf(x11, cw0[cc * 4 + 3], a0v);
                    a1v = fmaf(x00, cw1[cc * 4 + 0], a1v);
                    a1v = fmaf(x01, cw1[cc * 4 + 1], a1v);
                    a1v = fmaf(x10, cw1[cc * 4 + 2], a1v);
                    a1v = fmaf(x11, cw1[cc * 4 + 3], a1v);
                }
                y0[rr] = elu_f(a0v);
                y1[rr] = elu_f(a1v);
            }
        } else {
            // slow path (row-crossing or K tail): per-position scalar loads
            #pragma unroll
            for (int rr = 0; rr < 4; rr++) {
                int r = r0 + rr;
                if (r < 638) {
                    int oh = (r * 565) >> 14;
                    const float* xp = xbase + oh * 30 + (r - oh * 29);
                    float a0v = cb0, a1v = cb1;
                    #pragma unroll
                    for (int cc = 0; cc < 3; cc++) {
                        float x00 = xp[cc * 690],      x01 = xp[cc * 690 + 1];
                        float x10 = xp[cc * 690 + 30], x11 = xp[cc * 690 + 31];
                        a0v = fmaf(x00, cw0[cc * 4 + 0], a0v);
                        a0v = fmaf(x01, cw0[cc * 4 + 1], a0v);
                        a0v = fmaf(x10, cw0[cc * 4 + 2], a0v);
                        a0v = fmaf(x11, cw0[cc * 4 + 3], a0v);
                        a1v = fmaf(x00, cw1[cc * 4 + 0], a1v);
                        a1v = fmaf(x01, cw1[cc * 4 + 1], a1v);
                        a1v = fmaf(x10, cw1[cc * 4 + 2], a1v);
                        a1v = fmaf(x11, cw1[cc * 4 + 3], a1v);
                    }
                    y0[rr] = elu_f(a0v);
                    y1[rr] = elu_f(a1v);
                } else { y0[rr] = 0.f; y1[rr] = 0.f; }
            }
        }
        #pragma unroll
        for (int j = 0; j < 4; j++) {
            unsigned short h0 = bf_hi(y0[j]);
            a_hi[j] = (short)h0;
            a_lo[j] = (short)bf_hi(y0[j] - __uint_as_float((unsigned)h0 << 16));
            unsigned short h1 = bf_hi(y1[j]);
            a_hi[4 + j] = (short)h1;
            a_lo[4 + j] = (short)bf_hi(y1[j] - __uint_as_float((unsigned)h1 << 16));
        }
    };

    if (use_bsp) {
        auto loadB = [&](int kc, bfrag* bh, bfrag* bl) {
            #pragma unroll
            for (int nt = 0; nt < 4; nt++) {
                size_t off = ((size_t)(kc * 16 + q * 4 + nt) * 16 + mn) * 8;
                bh[nt] = *(const bfrag*)(bhi + off);
                bl[nt] = *(const bfrag*)(blo + off);
            }
        };
        bfrag b_h[4], b_l[4], nb_h[4], nb_l[4];
        loadB(kc0, b_h, b_l);
        for (int kk = 0; kk < 40; kk++) {
            const int kc = kc0 + kk;
            bfrag a_hi, a_lo;
            convA(kc, a_hi, a_lo);
            if (kk < 39) loadB(kc + 1, nb_h, nb_l);   // prefetch before MFMAs
            #pragma unroll
            for (int nt = 0; nt < 4; nt++) {
                acc[nt] = __builtin_amdgcn_mfma_f32_16x16x32_bf16(a_hi, b_h[nt], acc[nt], 0, 0, 0);
                acc[nt] = __builtin_amdgcn_mfma_f32_16x16x32_bf16(a_hi, b_l[nt], acc[nt], 0, 0, 0);
                acc[nt] = __builtin_amdgcn_mfma_f32_16x16x32_bf16(a_lo, b_h[nt], acc[nt], 0, 0, 0);
            }
            #pragma unroll
            for (int nt = 0; nt < 4; nt++) { b_h[nt] = nb_h[nt]; b_l[nt] = nb_l[nt]; }
        }
    } else {
        // fallback: in-loop fp32 load + split (ws too small for pre-split B)
        for (int kk = 0; kk < 40; kk++) {
            const int kc = kc0 + kk;
            bfrag a_hi, a_lo;
            convA(kc, a_hi, a_lo);
            #pragma unroll
            for (int nt = 0; nt < 4; nt++) {
                int n = nt * 16 + mn;
                bfrag b_h, b_l;
                #pragma unroll
                for (int j = 0; j < 8; j++) {
                    int o = o0 + (j >> 2);
                    int r = kc * 4 + (j & 3);
                    float vv = (r < 638) ? fc1_w[(size_t)n * KTOT + o * 638 + r] : 0.f;
                    unsigned short h = bf_hi(vv);
                    b_h[j] = (short)h;
                    b_l[j] = (short)bf_hi(vv - __uint_as_float((unsigned)h << 16));
                }
                acc[nt] = __builtin_amdgcn_mfma_f32_16x16x32_bf16(a_hi, b_h, acc[nt], 0, 0, 0);
                acc[nt] = __builtin_amdgcn_mfma_f32_16x16x32_bf16(a_hi, b_l, acc[nt], 0, 0, 0);
                acc[nt] = __builtin_amdgcn_mfma_f32_16x16x32_bf16(a_lo, b_h, acc[nt], 0, 0, 0);
            }
        }
    }

    // ---- cross-wave K reduction: partials -> LDS -> sum + bias + ReLU ----
    // C/D layout: col = lane&15 -> n-within-tile, row = q*4 + reg -> m.
    #pragma unroll
    for (int nt = 0; nt < 4; nt++) {
        int n = nt * 16 + mn;
        #pragma unroll
        for (int rg = 0; rg < 4; rg++) {
            int m = q * 4 + rg;
            redS[(wv * 16 + m) * 64 + n] = acc[nt][rg];
        }
    }
    __syncthreads();
    #pragma unroll
    for (int e = 0; e < 4; e++) {
        int flat = e * 256 + t;           // 1024 = 16*64
        int m = flat >> 6, n = flat & 63;
        float s = redS[m * 64 + n] + redS[(16 + m) * 64 + n]
                + redS[(32 + m) * 64 + n] + redS[(48 + m) * 64 + n];
        hS[m * 68 + n] = fmaxf(s + fc1_b[n], 0.f);
    }
    // ---- stage fc2 weights ----
    #pragma unroll
    for (int e = 0; e < 8; e++) {
        int flat = e * 256 + t;           // 2048 = 32*64
        int s = flat >> 6, n = flat & 63;
        w2S[s * 65 + n] = fc2_w[flat];
    }
    __syncthreads();

    // ---- fc2 + input affine -> seq (16 samples x 32 sensory) ----
    #pragma unroll
    for (int e = 0; e < 2; e++) {
        int flat = e * 256 + t;           // 512 = 16*32
        int s = flat & 31, bl = flat >> 5;
        float a2 = fc2_b[s];
        #pragma unroll 8
        for (int n = 0; n < 64; n++)
            a2 = fmaf(hS[bl * 68 + n], w2S[s * 65 + n], a2);
        seqS[bl * 33 + s] = a2 * iw[s] + ib[s];
    }
    __syncthreads();

    // ---- sensory synapse sums (16 samples x 19 neurons = 304 items) ----
    #pragma unroll
    for (int e = 0; e < 2; e++) {
        int flat = e * 256 + t;
        if (flat < 304) {
            int n = flat % 19, bl = flat / 19;
            float wn = 0.f, wd = 0.f;
            #pragma unroll
            for (int s = 0; s < 32; s++) {
                float xx = sc0[s * 19 + n] - sc1[s * 19 + n] * seqS[bl * 33 + s];
                float ee = __builtin_amdgcn_exp2f(xx);
                float uu = __builtin_amdgcn_rcpf(1.f + ee);
                wn = fmaf(swe[s * 19 + n], uu, wn);
                wd = fmaf(swp[s * 19 + n], uu, wd);
            }
            wn_s[(b0 + bl) * 19 + n] = wn;
            wd_s[(b0 + bl) * 19 + n] = wd;
        }
    }
}

// ---------------------------------------------------------------------------
// K3P v3: chunk-parallel LTC scan, one wave per chunk — UNCHANGED (isolating
// the k12 memory fix; scan should surface in top-5 once k12 < ~150 us).
// ---------------------------------------------------------------------------
__global__ __launch_bounds__(64, 1) void k3p2_scan(
    const float* __restrict__ wn_s, const float* __restrict__ wd_s,
    const float* __restrict__ rc1, const float* __restrict__ rc0,
    const float* __restrict__ rwe, const float* __restrict__ rwp,
    const float* __restrict__ neu,
    const float* __restrict__ out_w, const float* __restrict__ out_b,
    float* __restrict__ out)
{
    const int l    = threadIdx.x;       // 0..63
    const int col  = l & 31;            // target neuron (19 real + 13 pad)
    const int p    = l >> 5;            // source half
    const int cidx = (col < 19) ? col : 0;

    float ca[10], cb[10], cwe[10], cwp[10];
    int gidx[10];
    #pragma unroll
    for (int j = 0; j < 10; j++) {
        int s = p * 10 + j;
        bool e = (col < 19) && (s < 19);
        int idx = e ? (s * 19 + col) : 0;
        ca[j]  = e ? rc1[idx] : 0.f;
        cb[j]  = e ? rc0[idx] : 0.f;
        cwe[j] = e ? rwe[idx] : 0.f;
        cwp[j] = e ? rwp[idx] : 0.f;
        gidx[j] = ((s < 19) ? s : 0) * 4;
    }

    const float cmt  = neu[cidx];
    const float gvl  = neu[64 + cidx];
    const float den0 = neu[128 + cidx];
    const float owv  = out_w[0];
    const float obv  = out_b[0];

    const int c       = blockIdx.x;
    const int s_out   = c * S_PER;
    const int s_begin = (s_out > WARM) ? (s_out - WARM) : 0;
    const int s_end   = s_out + S_PER;
    const int pidx    = (l ^ 32) * 4;

    float v = 0.f;
    float wnc = wn_s[s_begin * 19 + cidx];
    float wdc = wd_s[s_begin * 19 + cidx];

    for (int tt = s_begin; tt < s_end; tt++) {
        int nt = (tt + 1 < T_STEPS) ? (tt + 1) : (T_STEPS - 1);
        float wnn = wn_s[nt * 19 + cidx];
        float wdn = wd_s[nt * 19 + cidx];

        #pragma unroll
        for (int u = 0; u < 6; u++) {
            float pn = 0.f, pd = 0.f;
            #pragma unroll
            for (int j = 0; j < 10; j++) {
                float vs = __int_as_float(
                    __builtin_amdgcn_ds_bpermute(gidx[j], __float_as_int(v)));
                float xx = cb[j] - ca[j] * vs;
                float ee = __builtin_amdgcn_exp2f(xx);
                float uu = __builtin_amdgcn_rcpf(1.f + ee);
                pn = fmaf(cwe[j], uu, pn);
                pd = fmaf(cwp[j], uu, pd);
            }
            pn += __int_as_float(__builtin_amdgcn_ds_bpermute(pidx, __float_as_int(pn)));
            pd += __int_as_float(__builtin_amdgcn_ds_bpermute(pidx, __float_as_int(pd)));
            float num = fmaf(cmt, v, gvl) + (pn + wnc);
            float den = den0 + pd + wdc;
            v = num * __builtin_amdgcn_rcpf(den);
        }
        if (l == 0 && tt >= s_out) out[tt] = fmaf(v, owv, obv);
        wnc = wnn; wdc = wdn;
    }
}

// ---------------------------------------------------------------------------
extern "C" void kernel_launch(void* const* d_in, const int* in_sizes, int n_in,
                              void* d_out, int out_size, void* d_ws, size_t ws_size,
                              hipStream_t stream) {
    const float* x      = (const float*)d_in[0];
    const float* conv_w = (const float*)d_in[1];
    const float* conv_b = (const float*)d_in[2];
    const float* fc1_w  = (const float*)d_in[3];
    const float* fc1_b  = (const float*)d_in[4];
    const float* fc2_w  = (const float*)d_in[5];
    const float* fc2_b  = (const float*)d_in[6];
    const float* iw     = (const float*)d_in[7];
    const float* ib     = (const float*)d_in[8];
    const float* sw     = (const float*)d_in[9];
    const float* smu    = (const float*)d_in[10];
    const float* ssig   = (const float*)d_in[11];
    const float* serev  = (const float*)d_in[12];
    const float* smask  = (const float*)d_in[13];
    const float* w      = (const float*)d_in[14];
    const float* mu     = (const float*)d_in[15];
    const float* sigma  = (const float*)d_in[16];
    const float* erev   = (const float*)d_in[17];
    const float* mask   = (const float*)d_in[18];
    const float* gleak  = (const float*)d_in[19];
    const float* vleak  = (const float*)d_in[20];
    const float* cm     = (const float*)d_in[21];
    const float* ow     = (const float*)d_in[22];
    const float* ob     = (const float*)d_in[23];

    float* ws   = (float*)d_ws;
    float* wn_s = ws;                    // 8192*19 = 155648
    float* wd_s = wn_s + 155648;         // 155648
    float* sc1  = wd_s + 155648;         // 640 each
    float* sc0  = sc1 + 640;
    float* swe  = sc0 + 640;
    float* swp  = swe + 640;
    float* rc1  = swp + 640;             // 384 each
    float* rc0  = rc1 + 384;
    float* rwe  = rc0 + 384;
    float* rwp  = rwe + 384;
    float* neu  = rwp + 384;             // 192  (base ends at 315,584 floats)
    const int use_bsp = (ws_size >= (size_t)WS_NEED_BSP) ? 1 : 0;
    unsigned short* bhi = (unsigned short*)(ws + WS_BASE_FLOATS);
    unsigned short* blo = bhi + 64 * KP;
    (void)in_sizes; (void)n_in; (void)out_size;

    hipLaunchKernelGGL(k0_precompute, dim3(1), dim3(640), 0, stream,
        sw, smu, ssig, serev, smask, w, mu, sigma, erev, mask,
        gleak, vleak, cm, sc1, sc0, swe, swp, rc1, rc0, rwe, rwp, neu);

    if (use_bsp) {
        hipLaunchKernelGGL(k0b_splitB, dim3(64 * KP / 256), dim3(256), 0, stream,
            fc1_w, bhi, blo);
    }

    hipLaunchKernelGGL(k12_frontend, dim3(512), dim3(256), 0, stream,
        x, conv_w, conv_b, fc1_w, fc1_b, fc2_w, fc2_b, iw, ib,
        sc1, sc0, swe, swp, bhi, blo, use_bsp, wn_s, wd_s);

    hipLaunchKernelGGL(k3p2_scan, dim3(SCAN_CHUNKS), dim3(64), 0, stream,
        wn_s, wd_s, rc1, rc0, rwe, rwp, neu, ow, ob, (float*)d_out);
}

// Round 10
// 364.693 us; speedup vs baseline: 3.5062x; 1.0071x over previous
//
#include <hip/hip_runtime.h>
#include <hip/hip_bf16.h>
#include <math.h>

#define L2E 1.4426950408889634f
#define T_STEPS 8192
#define KTOT 5104   // 8 channels * 638 spatial (22*29)
#define EPS_LTC 1e-8f
#define KP 5120     // permuted/padded K (160 chunks x 32)

// scan chunking: 1024 chunks x 8 steps, 16-step burn-in (chunks 0,1 exact).
#define SCAN_CHUNKS 1024
#define S_PER  8
#define WARM   16

// ws layout (floats): base 315,584 f = 1,262,336 B; optional pre-split B adds
// 2 x 327,680 ushorts = 1,310,720 B  ->  total 2,573,056 B (gated on ws_size).
#define WS_BASE_FLOATS 315584
#define WS_NEED_BSP    2573056

typedef __attribute__((ext_vector_type(8))) short bfrag;   // 8 bf16 (4 VGPR)
typedef __attribute__((ext_vector_type(4))) float ffrag;   // 4 fp32 acc
typedef __attribute__((ext_vector_type(4))) float fvec4;

__device__ __forceinline__ float softplus_f(float x) {
    return log1pf(expf(-fabsf(x))) + fmaxf(x, 0.f);
}

__device__ __forceinline__ unsigned short bf_hi(float f) {  // RNE fp32->bf16
    unsigned u = __float_as_uint(f);
    u = u + 0x7FFFu + ((u >> 16) & 1u);
    return (unsigned short)(u >> 16);
}

__device__ __forceinline__ float elu_f(float x) {
    return (x > 0.f) ? x : (__builtin_amdgcn_exp2f(x * L2E) - 1.f);
}

// ---------------------------------------------------------------------------
// K0: parameter precompute (tiny).
// ---------------------------------------------------------------------------
__global__ void k0_precompute(
    const float* __restrict__ sw, const float* __restrict__ smu,
    const float* __restrict__ ssig, const float* __restrict__ serev,
    const float* __restrict__ smask,
    const float* __restrict__ w, const float* __restrict__ mu,
    const float* __restrict__ sigma, const float* __restrict__ erev,
    const float* __restrict__ mask,
    const float* __restrict__ gleak, const float* __restrict__ vleak,
    const float* __restrict__ cm,
    float* __restrict__ sc1, float* __restrict__ sc0,
    float* __restrict__ swe, float* __restrict__ swp,
    float* __restrict__ rc1, float* __restrict__ rc0,
    float* __restrict__ rwe, float* __restrict__ rwp,
    float* __restrict__ neu)
{
    int t = threadIdx.x;
    if (t < 608) {   // sensory (32 x 19)
        float sp = softplus_f(sw[t]);
        float c1 = ssig[t] * L2E;
        sc1[t] = c1;
        sc0[t] = c1 * smu[t];
        swe[t] = sp * serev[t];
        swp[t] = sp * smask[t];
    }
    if (t < 361) {   // recurrent (19 x 19), layout [src*19 + tgt]
        float wp = softplus_f(w[t]) * mask[t];
        float c1 = sigma[t] * L2E;
        rc1[t] = c1;
        rc0[t] = c1 * mu[t];
        rwe[t] = wp * erev[t];
        rwp[t] = wp;
    }
    if (t < 64) {
        if (t < 19) {
            float g   = softplus_f(gleak[t]);
            float cmt = softplus_f(cm[t]) * 6.f;   // ODE_UNFOLDS
            neu[t]       = cmt;
            neu[64 + t]  = g * vleak[t];
            neu[128 + t] = cmt + g + EPS_LTC;
        } else {
            neu[t] = 0.f; neu[64 + t] = 0.f; neu[128 + t] = 1.f;
        }
    }
}

// ---------------------------------------------------------------------------
// K0B v2: pre-split fc1_w into bf16 hi/lo, FRAGMENT-INTERLEAVED:
// g = (((kc*16 + q*4 + nt)*16) + mn)*8 + j ; n = nt*16+mn ; o = 2q + (j>>2) ;
// r = kc*4 + (j&3). A wave's per-(kc) B-read is 8 KB contiguous.
// ---------------------------------------------------------------------------
__global__ __launch_bounds__(256) void k0b_splitB(
    const float* __restrict__ fc1_w,
    unsigned short* __restrict__ bhi, unsigned short* __restrict__ blo)
{
    int g = blockIdx.x * 256 + threadIdx.x;   // 0 .. 64*KP-1
    int j  = g & 7;
    int mn = (g >> 3) & 15;
    int nt = (g >> 7) & 3;
    int q  = (g >> 9) & 3;
    int kc = g >> 11;
    int n  = nt * 16 + mn;
    int o  = 2 * q + (j >> 2);
    int r  = kc * 4 + (j & 3);
    float v = (r < 638) ? fc1_w[n * KTOT + o * 638 + r] : 0.f;
    unsigned short h = bf_hi(v);
    bhi[g] = h;
    blo[g] = bf_hi(v - __uint_as_float((unsigned)h << 16));
}

// ---------------------------------------------------------------------------
// K12 v10: latency-hiding via TLP.
//  - 512 blocks x 512 thr, __launch_bounds__(512,4): 2 blocks/CU x 8 waves
//    = 16 waves/CU = 4 waves/SIMD (R9 had 2/SIMD and was miss-latency-bound:
//    MfmaUtil 4%, VALUBusy 20%, HBM 22% -- nothing saturated).
//  - 8-way K-split: wave w covers kc in [20w, 20w+20); K-loop body identical
//    to R9 (register conv A, interleaved pre-split B, depth-1 B prefetch,
//    VGPR ~84 <= 128 so the 4/SIMD occupancy holds).
//  - Epilogue: 8 partial Cs reduced via 32 KB LDS (2 barriers total).
// ---------------------------------------------------------------------------
__global__ __launch_bounds__(512, 4) void k12_frontend(
    const float* __restrict__ x, const float* __restrict__ conv_w,
    const float* __restrict__ conv_b,
    const float* __restrict__ fc1_w, const float* __restrict__ fc1_b,
    const float* __restrict__ fc2_w, const float* __restrict__ fc2_b,
    const float* __restrict__ iw, const float* __restrict__ ib,
    const float* __restrict__ sc1, const float* __restrict__ sc0,
    const float* __restrict__ swe, const float* __restrict__ swp,
    const unsigned short* __restrict__ bhi,
    const unsigned short* __restrict__ blo, int use_bsp,
    float* __restrict__ wn_s, float* __restrict__ wd_s)
{
    __shared__ __align__(16) float smem[11920];
    float* redS = smem;            // [8][16][64] = 8192 f partial-C buffer
    float* hS   = smem + 8192;     // 16 x 68 = 1088 f
    float* w2S  = smem + 9312;     // [s][n] stride 65, 2080 f
    float* seqS = smem + 11392;    // [sample][s] stride 33, 528 f

    const int t    = threadIdx.x;   // 0..511
    const int b0   = blockIdx.x * 16;
    const int lane = t & 63;
    const int wv   = t >> 6;        // wave 0..7 -> K eighth
    const int q    = lane >> 4;     // quad -> channel pair 2q,2q+1
    const int mn   = lane & 15;     // sample (A) / out-within-tile (B)
    const int o0   = 2 * q;

    // conv weights + bias for this lane's channel pair, in registers
    float cw0[12], cw1[12];
    #pragma unroll
    for (int i = 0; i < 12; i++) {
        cw0[i] = conv_w[o0 * 12 + i];
        cw1[i] = conv_w[o0 * 12 + 12 + i];
    }
    const float cb0 = conv_b[o0], cb1 = conv_b[o0 + 1];
    const float* xbase = x + (size_t)(b0 + mn) * 2070;

    ffrag acc[4];
    #pragma unroll
    for (int nt = 0; nt < 4; nt++) acc[nt] = (ffrag){0.f, 0.f, 0.f, 0.f};

    const int kc0 = wv * 20;

    // conv+ELU -> split-bf16 A fragments for chunk kc (all in registers)
    auto convA = [&](int kc, bfrag& a_hi, bfrag& a_lo) {
        float y0[4], y1[4];
        int r0  = kc * 4;
        int oh0 = (r0 * 565) >> 14;          // == r0/29 for r0 <= 637
        int ow0 = r0 - oh0 * 29;
        if (ow0 <= 25 && r0 + 3 <= 637) {
            // fast path: all 4 positions in conv row oh0; shared 2x5 window
            float xr[3][2][5];
            #pragma unroll
            for (int cc = 0; cc < 3; cc++) {
                const float* a0 = xbase + cc * 690 + oh0 * 30 + ow0;
                fvec4 v0, v1;
                __builtin_memcpy(&v0, a0, 16);
                __builtin_memcpy(&v1, a0 + 30, 16);
                xr[cc][0][0] = v0.x; xr[cc][0][1] = v0.y;
                xr[cc][0][2] = v0.z; xr[cc][0][3] = v0.w;
                xr[cc][0][4] = a0[4];
                xr[cc][1][0] = v1.x; xr[cc][1][1] = v1.y;
                xr[cc][1][2] = v1.z; xr[cc][1][3] = v1.w;
                xr[cc][1][4] = a0[34];
            }
            #pragma unroll
            for (int rr = 0; rr < 4; rr++) {
                float a0v = cb0, a1v = cb1;
                #pragma unroll
                for (int cc = 0; cc < 3; cc++) {
                    float x00 = xr[cc][0][rr], x01 = xr[cc][0][rr + 1];
                    float x10 = xr[cc][1][rr], x11 = xr[cc][1][rr + 1];
                    a0v = fmaf(x00, cw0[cc * 4 + 0], a0v);
                    a0v = fmaf(x01, cw0[cc * 4 + 1], a0v);
                    a0v = fmaf(x10, cw0[cc * 4 + 2], a0v);
                    a0v = fmaf(x11, cw0[cc * 4 + 3], a0v);
                    a1v = fmaf(x00, cw1[cc * 4 + 0], a1v);
                    a1v = fmaf(x01, cw1[cc * 4 + 1], a1v);
                    a1v = fmaf(x10, cw1[cc * 4 + 2], a1v);
                    a1v = fmaf(x11, cw1[cc * 4 + 3], a1v);
                }
                y0[rr] = elu_f(a0v);
                y1[rr] = elu_f(a1v);
            }
        } else {
            // slow path (row-crossing or K tail): per-position scalar loads
            #pragma unroll
            for (int rr = 0; rr < 4; rr++) {
                int r = r0 + rr;
                if (r < 638) {
                    int oh = (r * 565) >> 14;
                    const float* xp = xbase + oh * 30 + (r - oh * 29);
                    float a0v = cb0, a1v = cb1;
                    #pragma unroll
                    for (int cc = 0; cc < 3; cc++) {
                        float x00 = xp[cc * 690],      x01 = xp[cc * 690 + 1];
                        float x10 = xp[cc * 690 + 30], x11 = xp[cc * 690 + 31];
                        a0v = fmaf(x00, cw0[cc * 4 + 0], a0v);
                        a0v = fmaf(x01, cw0[cc * 4 + 1], a0v);
                        a0v = fmaf(x10, cw0[cc * 4 + 2], a0v);
                        a0v = fmaf(x11, cw0[cc * 4 + 3], a0v);
                        a1v = fmaf(x00, cw1[cc * 4 + 0], a1v);
                        a1v = fmaf(x01, cw1[cc * 4 + 1], a1v);
                        a1v = fmaf(x10, cw1[cc * 4 + 2], a1v);
                        a1v = fmaf(x11, cw1[cc * 4 + 3], a1v);
                    }
                    y0[rr] = elu_f(a0v);
                    y1[rr] = elu_f(a1v);
                } else { y0[rr] = 0.f; y1[rr] = 0.f; }
            }
        }
        #pragma unroll
        for (int j = 0; j < 4; j++) {
            unsigned short h0 = bf_hi(y0[j]);
            a_hi[j] = (short)h0;
            a_lo[j] = (short)bf_hi(y0[j] - __uint_as_float((unsigned)h0 << 16));
            unsigned short h1 = bf_hi(y1[j]);
            a_hi[4 + j] = (short)h1;
            a_lo[4 + j] = (short)bf_hi(y1[j] - __uint_as_float((unsigned)h1 << 16));
        }
    };

    if (use_bsp) {
        auto loadB = [&](int kc, bfrag* bh, bfrag* bl) {
            #pragma unroll
            for (int nt = 0; nt < 4; nt++) {
                size_t off = ((size_t)(kc * 16 + q * 4 + nt) * 16 + mn) * 8;
                bh[nt] = *(const bfrag*)(bhi + off);
                bl[nt] = *(const bfrag*)(blo + off);
            }
        };
        bfrag b_h[4], b_l[4], nb_h[4], nb_l[4];
        loadB(kc0, b_h, b_l);
        for (int kk = 0; kk < 20; kk++) {
            const int kc = kc0 + kk;
            bfrag a_hi, a_lo;
            convA(kc, a_hi, a_lo);
            if (kk < 19) loadB(kc + 1, nb_h, nb_l);   // prefetch before MFMAs
            #pragma unroll
            for (int nt = 0; nt < 4; nt++) {
                acc[nt] = __builtin_amdgcn_mfma_f32_16x16x32_bf16(a_hi, b_h[nt], acc[nt], 0, 0, 0);
                acc[nt] = __builtin_amdgcn_mfma_f32_16x16x32_bf16(a_hi, b_l[nt], acc[nt], 0, 0, 0);
                acc[nt] = __builtin_amdgcn_mfma_f32_16x16x32_bf16(a_lo, b_h[nt], acc[nt], 0, 0, 0);
            }
            #pragma unroll
            for (int nt = 0; nt < 4; nt++) { b_h[nt] = nb_h[nt]; b_l[nt] = nb_l[nt]; }
        }
    } else {
        // fallback: in-loop fp32 load + split (ws too small for pre-split B)
        for (int kk = 0; kk < 20; kk++) {
            const int kc = kc0 + kk;
            bfrag a_hi, a_lo;
            convA(kc, a_hi, a_lo);
            #pragma unroll
            for (int nt = 0; nt < 4; nt++) {
                int n = nt * 16 + mn;
                bfrag b_h, b_l;
                #pragma unroll
                for (int j = 0; j < 8; j++) {
                    int o = o0 + (j >> 2);
                    int r = kc * 4 + (j & 3);
                    float vv = (r < 638) ? fc1_w[(size_t)n * KTOT + o * 638 + r] : 0.f;
                    unsigned short h = bf_hi(vv);
                    b_h[j] = (short)h;
                    b_l[j] = (short)bf_hi(vv - __uint_as_float((unsigned)h << 16));
                }
                acc[nt] = __builtin_amdgcn_mfma_f32_16x16x32_bf16(a_hi, b_h, acc[nt], 0, 0, 0);
                acc[nt] = __builtin_amdgcn_mfma_f32_16x16x32_bf16(a_hi, b_l, acc[nt], 0, 0, 0);
                acc[nt] = __builtin_amdgcn_mfma_f32_16x16x32_bf16(a_lo, b_h, acc[nt], 0, 0, 0);
            }
        }
    }

    // ---- cross-wave K reduction: 8 partials -> LDS -> sum + bias + ReLU ----
    // C/D layout: col = lane&15 -> n-within-tile, row = q*4 + reg -> m.
    #pragma unroll
    for (int nt = 0; nt < 4; nt++) {
        int n = nt * 16 + mn;
        #pragma unroll
        for (int rg = 0; rg < 4; rg++) {
            int m = q * 4 + rg;
            redS[(wv * 16 + m) * 64 + n] = acc[nt][rg];
        }
    }
    __syncthreads();
    #pragma unroll
    for (int e = 0; e < 2; e++) {
        int flat = e * 512 + t;           // 1024 = 16*64
        int m = flat >> 6, n = flat & 63;
        float s = 0.f;
        #pragma unroll
        for (int p = 0; p < 8; p++) s += redS[(p * 16 + m) * 64 + n];
        hS[m * 68 + n] = fmaxf(s + fc1_b[n], 0.f);
    }
    // ---- stage fc2 weights ----
    #pragma unroll
    for (int e = 0; e < 4; e++) {
        int flat = e * 512 + t;           // 2048 = 32*64
        int s = flat >> 6, n = flat & 63;
        w2S[s * 65 + n] = fc2_w[flat];
    }
    __syncthreads();

    // ---- fc2 + input affine -> seq (16 samples x 32 sensory = 512 items) ----
    {
        int s = t & 31, bl = t >> 5;
        float a2 = fc2_b[s];
        #pragma unroll 8
        for (int n = 0; n < 64; n++)
            a2 = fmaf(hS[bl * 68 + n], w2S[s * 65 + n], a2);
        seqS[bl * 33 + s] = a2 * iw[s] + ib[s];
    }
    __syncthreads();

    // ---- sensory synapse sums (16 samples x 19 neurons = 304 items) ----
    if (t < 304) {
        int n = t % 19, bl = t / 19;
        float wn = 0.f, wd = 0.f;
        #pragma unroll
        for (int s = 0; s < 32; s++) {
            float xx = sc0[s * 19 + n] - sc1[s * 19 + n] * seqS[bl * 33 + s];
            float ee = __builtin_amdgcn_exp2f(xx);
            float uu = __builtin_amdgcn_rcpf(1.f + ee);
            wn = fmaf(swe[s * 19 + n], uu, wn);
            wd = fmaf(swp[s * 19 + n], uu, wd);
        }
        wn_s[(b0 + bl) * 19 + n] = wn;
        wd_s[(b0 + bl) * 19 + n] = wd;
    }
}

// ---------------------------------------------------------------------------
// K3P v3: chunk-parallel LTC scan, one wave per chunk — UNCHANGED (will
// surface in top-5 counters once k12 drops below it).
// ---------------------------------------------------------------------------
__global__ __launch_bounds__(64, 1) void k3p2_scan(
    const float* __restrict__ wn_s, const float* __restrict__ wd_s,
    const float* __restrict__ rc1, const float* __restrict__ rc0,
    const float* __restrict__ rwe, const float* __restrict__ rwp,
    const float* __restrict__ neu,
    const float* __restrict__ out_w, const float* __restrict__ out_b,
    float* __restrict__ out)
{
    const int l    = threadIdx.x;       // 0..63
    const int col  = l & 31;            // target neuron (19 real + 13 pad)
    const int p    = l >> 5;            // source half
    const int cidx = (col < 19) ? col : 0;

    float ca[10], cb[10], cwe[10], cwp[10];
    int gidx[10];
    #pragma unroll
    for (int j = 0; j < 10; j++) {
        int s = p * 10 + j;
        bool e = (col < 19) && (s < 19);
        int idx = e ? (s * 19 + col) : 0;
        ca[j]  = e ? rc1[idx] : 0.f;
        cb[j]  = e ? rc0[idx] : 0.f;
        cwe[j] = e ? rwe[idx] : 0.f;
        cwp[j] = e ? rwp[idx] : 0.f;
        gidx[j] = ((s < 19) ? s : 0) * 4;
    }

    const float cmt  = neu[cidx];
    const float gvl  = neu[64 + cidx];
    const float den0 = neu[128 + cidx];
    const float owv  = out_w[0];
    const float obv  = out_b[0];

    const int c       = blockIdx.x;
    const int s_out   = c * S_PER;
    const int s_begin = (s_out > WARM) ? (s_out - WARM) : 0;
    const int s_end   = s_out + S_PER;
    const int pidx    = (l ^ 32) * 4;

    float v = 0.f;
    float wnc = wn_s[s_begin * 19 + cidx];
    float wdc = wd_s[s_begin * 19 + cidx];

    for (int tt = s_begin; tt < s_end; tt++) {
        int nt = (tt + 1 < T_STEPS) ? (tt + 1) : (T_STEPS - 1);
        float wnn = wn_s[nt * 19 + cidx];
        float wdn = wd_s[nt * 19 + cidx];

        #pragma unroll
        for (int u = 0; u < 6; u++) {
            float pn = 0.f, pd = 0.f;
            #pragma unroll
            for (int j = 0; j < 10; j++) {
                float vs = __int_as_float(
                    __builtin_amdgcn_ds_bpermute(gidx[j], __float_as_int(v)));
                float xx = cb[j] - ca[j] * vs;
                float ee = __builtin_amdgcn_exp2f(xx);
                float uu = __builtin_amdgcn_rcpf(1.f + ee);
                pn = fmaf(cwe[j], uu, pn);
                pd = fmaf(cwp[j], uu, pd);
            }
            pn += __int_as_float(__builtin_amdgcn_ds_bpermute(pidx, __float_as_int(pn)));
            pd += __int_as_float(__builtin_amdgcn_ds_bpermute(pidx, __float_as_int(pd)));
            float num = fmaf(cmt, v, gvl) + (pn + wnc);
            float den = den0 + pd + wdc;
            v = num * __builtin_amdgcn_rcpf(den);
        }
        if (l == 0 && tt >= s_out) out[tt] = fmaf(v, owv, obv);
        wnc = wnn; wdc = wdn;
    }
}

// ---------------------------------------------------------------------------
extern "C" void kernel_launch(void* const* d_in, const int* in_sizes, int n_in,
                              void* d_out, int out_size, void* d_ws, size_t ws_size,
                              hipStream_t stream) {
    const float* x      = (const float*)d_in[0];
    const float* conv_w = (const float*)d_in[1];
    const float* conv_b = (const float*)d_in[2];
    const float* fc1_w  = (const float*)d_in[3];
    const float* fc1_b  = (const float*)d_in[4];
    const float* fc2_w  = (const float*)d_in[5];
    const float* fc2_b  = (const float*)d_in[6];
    const float* iw     = (const float*)d_in[7];
    const float* ib     = (const float*)d_in[8];
    const float* sw     = (const float*)d_in[9];
    const float* smu    = (const float*)d_in[10];
    const float* ssig   = (const float*)d_in[11];
    const float* serev  = (const float*)d_in[12];
    const float* smask  = (const float*)d_in[13];
    const float* w      = (const float*)d_in[14];
    const float* mu     = (const float*)d_in[15];
    const float* sigma  = (const float*)d_in[16];
    const float* erev   = (const float*)d_in[17];
    const float* mask   = (const float*)d_in[18];
    const float* gleak  = (const float*)d_in[19];
    const float* vleak  = (const float*)d_in[20];
    const float* cm     = (const float*)d_in[21];
    const float* ow     = (const float*)d_in[22];
    const float* ob     = (const float*)d_in[23];

    float* ws   = (float*)d_ws;
    float* wn_s = ws;                    // 8192*19 = 155648
    float* wd_s = wn_s + 155648;         // 155648
    float* sc1  = wd_s + 155648;         // 640 each
    float* sc0  = sc1 + 640;
    float* swe  = sc0 + 640;
    float* swp  = swe + 640;
    float* rc1  = swp + 640;             // 384 each
    float* rc0  = rc1 + 384;
    float* rwe  = rc0 + 384;
    float* rwp  = rwe + 384;
    float* neu  = rwp + 384;             // 192  (base ends at 315,584 floats)
    const int use_bsp = (ws_size >= (size_t)WS_NEED_BSP) ? 1 : 0;
    unsigned short* bhi = (unsigned short*)(ws + WS_BASE_FLOATS);
    unsigned short* blo = bhi + 64 * KP;
    (void)in_sizes; (void)n_in; (void)out_size;

    hipLaunchKernelGGL(k0_precompute, dim3(1), dim3(640), 0, stream,
        sw, smu, ssig, serev, smask, w, mu, sigma, erev, mask,
        gleak, vleak, cm, sc1, sc0, swe, swp, rc1, rc0, rwe, rwp, neu);

    if (use_bsp) {
        hipLaunchKernelGGL(k0b_splitB, dim3(64 * KP / 256), dim3(256), 0, stream,
            fc1_w, bhi, blo);
    }

    hipLaunchKernelGGL(k12_frontend, dim3(512), dim3(512), 0, stream,
        x, conv_w, conv_b, fc1_w, fc1_b, fc2_w, fc2_b, iw, ib,
        sc1, sc0, swe, swp, bhi, blo, use_bsp, wn_s, wd_s);

    hipLaunchKernelGGL(k3p2_scan, dim3(SCAN_CHUNKS), dim3(64), 0, stream,
        wn_s, wd_s, rc1, rc0, rwe, rwp, neu, ow, ob, (float*)d_out);
}